// Round 1
// 600.928 us; speedup vs baseline: 1.0208x; 1.0208x over previous
//
#include <hip/hip_runtime.h>
#include <hip/hip_bf16.h>
#include <cstdio>

typedef unsigned short u16;
typedef __bf16 bf16x8 __attribute__((ext_vector_type(8)));
typedef float  floatx4 __attribute__((ext_vector_type(4)));

// ---------- scalar helpers ----------
__device__ __forceinline__ float bf2f(u16 u) {
  union { unsigned int i; float f; } v; v.i = ((unsigned int)u) << 16; return v.f;
}
__device__ __forceinline__ u16 f2bf(float f) {
  union { float f; unsigned int i; } v; v.f = f;
  unsigned int x = v.i;
  return (u16)((x + 0x7fffu + ((x >> 16) & 1u)) >> 16);   // RNE
}
__device__ __forceinline__ unsigned int f2bf_pk(float a, float b) {   // [lo=a, hi=b]
  __hip_bfloat162 h = __float22bfloat162_rn(make_float2(a, b));
  union { __hip_bfloat162 h; unsigned int u; } v; v.h = h; return v.u;
}
// fast gates: v_rcp (~1 ulp) + native exp — no IEEE div
__device__ __forceinline__ float sigmoidf_(float x) {
  return __builtin_amdgcn_rcpf(1.f + __expf(-x));
}
__device__ __forceinline__ float tanhf_(float x) {
  return fmaf(-2.f, __builtin_amdgcn_rcpf(1.f + __expf(2.f * x)), 1.f);
}

// LDS swizzle, 128-elem rows, 16B chunks: chunk' = chunk ^ (row&15)
__device__ __forceinline__ int swz128(int row, int c16) {
  return row * 128 + ((c16 ^ (row & 15)) << 3);
}
// element-level access into swizzled rows
__device__ __forceinline__ int swze(int row, int col) {
  return row * 128 + (((((col >> 3)) ^ (row & 15)) << 3) | (col & 7));
}

// ============ proj_e: Ep[v][col][4] = {i,u,o,f} pre-acts + biases (gate-interleaved) ============
// One block: 128 vocab rows x 128 cols x all 4 gates -> ushort4 coalesced stores.
__global__ __launch_bounds__(256, 2) void proj_e(
    const float* __restrict__ emb, const u16* __restrict__ WT,
    const float* __restrict__ bsum, u16* __restrict__ Ep)
{
  __shared__ __align__(16) u16 ldsA[128 * 128];
  const int tid = threadIdx.x;
  const long m0 = (long)blockIdx.x * 128;
  {
    const int r = tid >> 1, half = tid & 1;
    long row = m0 + r; if (row > 49999) row = 49999;
    const float* src = emb + row * 128 + half * 64;
#pragma unroll
    for (int i = 0; i < 8; i++) {
      float4 v0 = *reinterpret_cast<const float4*>(src + i * 8);
      float4 v1 = *reinterpret_cast<const float4*>(src + i * 8 + 4);
      unsigned int ov[4] = { f2bf_pk(v0.x, v0.y), f2bf_pk(v0.z, v0.w),
                             f2bf_pk(v1.x, v1.y), f2bf_pk(v1.z, v1.w) };
      *reinterpret_cast<uint4*>(&ldsA[swz128(r, half * 8 + i)]) =
          *reinterpret_cast<const uint4*>(ov);
    }
  }
  __syncthreads();
  const int lane = tid & 63, w = tid >> 6, l16 = lane & 15, quad = lane >> 4;
#pragma unroll
  for (int half = 0; half < 2; half++) {
    const int col = w * 32 + half * 16 + l16;
    bf16x8 bI[4], bU[4], bO[4], bF[4];
#pragma unroll
    for (int ks = 0; ks < 4; ks++) {
      const size_t o_ = ks * 32 + quad * 8;
      bI[ks] = *reinterpret_cast<const bf16x8*>(WT + (size_t)(0   + col) * 128 + o_);
      bU[ks] = *reinterpret_cast<const bf16x8*>(WT + (size_t)(128 + col) * 128 + o_);
      bO[ks] = *reinterpret_cast<const bf16x8*>(WT + (size_t)(256 + col) * 128 + o_);
      bF[ks] = *reinterpret_cast<const bf16x8*>(WT + (size_t)(384 + col) * 128 + o_);
    }
    const float bi = bsum[col], bu = bsum[128 + col], bo = bsum[256 + col], bf = bsum[384 + col];
#pragma unroll
    for (int i = 0; i < 8; i++) {
      floatx4 aI = {0.f,0.f,0.f,0.f}, aU = {0.f,0.f,0.f,0.f};
      floatx4 aO = {0.f,0.f,0.f,0.f}, aF = {0.f,0.f,0.f,0.f};
#pragma unroll
      for (int ks = 0; ks < 4; ks++) {
        bf16x8 a = *reinterpret_cast<const bf16x8*>(&ldsA[swz128(i * 16 + l16, ks * 4 + quad)]);
        aI = __builtin_amdgcn_mfma_f32_16x16x32_bf16(a, bI[ks], aI, 0, 0, 0);
        aU = __builtin_amdgcn_mfma_f32_16x16x32_bf16(a, bU[ks], aU, 0, 0, 0);
        aO = __builtin_amdgcn_mfma_f32_16x16x32_bf16(a, bO[ks], aO, 0, 0, 0);
        aF = __builtin_amdgcn_mfma_f32_16x16x32_bf16(a, bF[ks], aF, 0, 0, 0);
      }
#pragma unroll
      for (int r2 = 0; r2 < 4; r2++) {
        const long row = m0 + i * 16 + quad * 4 + r2;
        if (row < 50000) {
          u16 ov[4] = { f2bf(aI[r2] + bi), f2bf(aU[r2] + bu),
                        f2bf(aO[r2] + bo), f2bf(aF[r2] + bf) };
          *reinterpret_cast<ushort4*>(Ep + row * 512 + col * 4) =
              *reinterpret_cast<const ushort4*>(ov);
        }
      }
    }
  }
}

// ============ leaf_hc: vocab-level leaf activations Hl[v][128], Cl[v][128] ============
// Leaf nodes have h_sum = fc_sum = 0, so h/c depend only on the vocab id.
// 262144 leaves over 50000 words -> 5.2x less activation work + halved gather bytes in L4.
// Numerically identical to the old in-kernel path (same bf16 Ep inputs, same math, same RNE).
__global__ void leaf_hc(const u16* __restrict__ Ep,
                        u16* __restrict__ Hl, u16* __restrict__ Cl)
{
  const int tid = threadIdx.x;
  const int r = tid >> 6, c2 = tid & 63;           // 4 vocab rows/block, 2 cols/thread
  const size_t v = (size_t)blockIdx.x * 4 + r;     // grid = 12500 -> covers 50000 exactly
  uint4 g = *reinterpret_cast<const uint4*>(Ep + v * 512 + (size_t)c2 * 8);
  const u16* p = reinterpret_cast<const u16*>(&g); // {i,u,o,f} x 2 cols
  float c0 = sigmoidf_(bf2f(p[0])) * tanhf_(bf2f(p[1]));
  float c1 = sigmoidf_(bf2f(p[4])) * tanhf_(bf2f(p[5]));
  float h0 = sigmoidf_(bf2f(p[2])) * tanhf_(c0);
  float h1 = sigmoidf_(bf2f(p[6])) * tanhf_(c1);
  *reinterpret_cast<unsigned int*>(Hl + v * 128 + c2 * 2) = f2bf_pk(h0, h1);
  *reinterpret_cast<unsigned int*>(Cl + v * 128 + c2 * 2) = f2bf_pk(c0, c1);
}

// ============ k_level: per-i-tile fused f/i/u/o; gate-interleaved Ep; direct global c/h ============
// LEAF mode: h_prev/c_prev are the vocab-level Hl/Cl tables (indexed via sen gather).
template<int LR, bool LEAF>
__global__ __launch_bounds__(256, 2) void k_level(
    const int* __restrict__ sen, const u16* __restrict__ Ep,
    const u16* __restrict__ h_prev, const u16* __restrict__ c_prev,
    const u16* __restrict__ BfT, const u16* __restrict__ BihT,
    const u16* __restrict__ BuhT, const u16* __restrict__ BohT,
    u16* __restrict__ c_out, u16* __restrict__ h_out,
    long o0, long co0)
{
  constexpr int PM  = (LR == 2) ? 32 : 64;
  constexpr int CM  = PM << LR;
  constexpr int NCI = CM / 16;
  constexpr int RT  = 1 << LR;
  constexpr int RTI = 4 >> LR;         // parents per 4-row quad block
  constexpr int TPR = 256 / CM;        // staging threads per child row
  __shared__ __align__(16) u16 ldsA[CM * 128];            // child h (swz)
  __shared__ __align__(16) u16 ldsC[LEAF ? CM * 128 : 8]; // LEAF: child c (swz)
  __shared__ int sidP[PM];

  const int tid = threadIdx.x;
  const long p0 = (long)blockIdx.x * PM;
  const long cb = (long)blockIdx.x * CM;

  // ---- stage children ----
  {
    const int r = tid / TPR, q = tid % TPR;
    constexpr int CH = 16 / TPR;
    if (LEAF) {
      // pure gather of precomputed leaf h/c (256 B each, coalesced per row)
      const size_t v = (size_t)sen[co0 + cb + r];
      const u16* hs = h_prev + v * 128;
      const u16* cs = c_prev + v * 128;
#pragma unroll
      for (int ii = 0; ii < CH; ii++) {
        const int c16 = q * CH + ii;
        *reinterpret_cast<uint4*>(&ldsA[swz128(r, c16)]) =
            *reinterpret_cast<const uint4*>(hs + c16 * 8);
        *reinterpret_cast<uint4*>(&ldsC[swz128(r, c16)]) =
            *reinterpret_cast<const uint4*>(cs + c16 * 8);
      }
    } else {
      const u16* src = h_prev + (cb + r) * 128;
#pragma unroll
      for (int ii = 0; ii < CH; ii++) {
        const int c16 = q * CH + ii;
        *reinterpret_cast<uint4*>(&ldsA[swz128(r, c16)]) =
            *reinterpret_cast<const uint4*>(src + c16 * 8);
      }
    }
    if (tid < PM) sidP[tid] = sen[o0 + p0 + tid];
  }
  __syncthreads();

  const int lane = tid & 63, w = tid >> 6, l16 = lane & 15, quad = lane >> 4;

#pragma unroll
  for (int gl = 0; gl < 2; gl++) {
    const int col = w * 32 + gl * 16 + l16;
    bf16x8 bF[4], bI[4], bU[4], bO[4];
#pragma unroll
    for (int ks = 0; ks < 4; ks++) {
      const size_t bo_ = (size_t)col * 128 + ks * 32 + quad * 8;
      bF[ks] = *reinterpret_cast<const bf16x8*>(BfT + bo_);
      bI[ks] = *reinterpret_cast<const bf16x8*>(BihT + bo_);
      bU[ks] = *reinterpret_cast<const bf16x8*>(BuhT + bo_);
      bO[ks] = *reinterpret_cast<const bf16x8*>(BohT + bo_);
    }
#pragma unroll
    for (int i = 0; i < NCI; i++) {
      floatx4 aF = {0.f,0.f,0.f,0.f}, aI = {0.f,0.f,0.f,0.f};
      floatx4 aU = {0.f,0.f,0.f,0.f}, aO = {0.f,0.f,0.f,0.f};
#pragma unroll
      for (int ks = 0; ks < 4; ks++) {
        bf16x8 a = *reinterpret_cast<const bf16x8*>(&ldsA[swz128(i * 16 + l16, ks * 4 + quad)]);
        aF = __builtin_amdgcn_mfma_f32_16x16x32_bf16(a, bF[ks], aF, 0, 0, 0);
        aI = __builtin_amdgcn_mfma_f32_16x16x32_bf16(a, bI[ks], aI, 0, 0, 0);
        aU = __builtin_amdgcn_mfma_f32_16x16x32_bf16(a, bU[ks], aU, 0, 0, 0);
        aO = __builtin_amdgcn_mfma_f32_16x16x32_bf16(a, bO[ks], aO, 0, 0, 0);
      }
      const int rbase = i * 16 + quad * 4;
#pragma unroll
      for (int t = 0; t < RTI; t++) {
        const int p = (rbase >> LR) + t;
        // one 8-B load fetches all four gate pre-acts {i,u,o,f} for (parent, col)
        ushort4 g4 = *reinterpret_cast<const ushort4*>(Ep + (size_t)sidP[p] * 512 + col * 4);
        const float epf = bf2f(g4.w);
        float fsum = 0.f, isum = 0.f, usum = 0.f, osum = 0.f;
#pragma unroll
        for (int r2 = t * RT; r2 < t * RT + RT; r2++) {
          const int row = rbase + r2;
          const float cch = LEAF ? bf2f(ldsC[swze(row, col)])
                                 : bf2f(c_prev[(cb + row) * 128 + col]);
          fsum += sigmoidf_(aF[r2] + epf) * cch;
          isum += aI[r2]; usum += aU[r2]; osum += aO[r2];
        }
        const float c = sigmoidf_(isum + bf2f(g4.x)) * tanhf_(usum + bf2f(g4.y)) + fsum;
        const float h = sigmoidf_(osum + bf2f(g4.z)) * tanhf_(c);
        c_out[(p0 + p) * 128 + col] = f2bf(c);
        h_out[(p0 + p) * 128 + col] = f2bf(h);
      }
    }
  }
}

// ---------- weight/bias prep ----------
__global__ void build_wallT(const float* __restrict__ Wix, const float* __restrict__ Wux,
                            const float* __restrict__ Wox, const float* __restrict__ Wfx,
                            u16* __restrict__ WT)
{
  int idx = blockIdx.x * 256 + threadIdx.x;   // 512*128
  int n = idx >> 7, k = idx & 127;
  int g = n >> 7, j = n & 127;
  const float* W = (g == 0) ? Wix : (g == 1) ? Wux : (g == 2) ? Wox : Wfx;
  WT[idx] = f2bf(W[k * 128 + j]);
}

__global__ void build_bsum(const float* __restrict__ b_ix, const float* __restrict__ b_ih,
                           const float* __restrict__ b_ux, const float* __restrict__ b_uh,
                           const float* __restrict__ b_ox, const float* __restrict__ b_oh,
                           const float* __restrict__ b_fx, const float* __restrict__ b_fh,
                           float* __restrict__ bsum)
{
  int n = blockIdx.x * 256 + threadIdx.x;   // 512
  int g = n >> 7, j = n & 127;
  float v = (g == 0) ? b_ix[j] + b_ih[j] : (g == 1) ? b_ux[j] + b_uh[j]
          : (g == 2) ? b_ox[j] + b_oh[j] : b_fx[j] + b_fh[j];
  bsum[n] = v;
}

__global__ void build_bt128(const float* __restrict__ W, u16* __restrict__ BT) {
  int idx = blockIdx.x * 256 + threadIdx.x;   // 128*128
  int n = idx >> 7, k = idx & 127;
  BT[idx] = f2bf(W[k * 128 + n]);
}

// ---------- output projection (4096 x 4, tiny) ----------
__global__ void out_proj(const u16* __restrict__ h_root, const float* __restrict__ W_out,
                         const float* __restrict__ b_out, float* __restrict__ out)
{
  int idx = blockIdx.x * 256 + threadIdx.x;   // 4096*4
  int n = idx >> 2, cls = idx & 3;
  float s = b_out[cls];
  for (int k = 0; k < 128; k++)
    s += bf2f(h_root[(long)n * 128 + k]) * W_out[k * 4 + cls];
  out[idx] = s;
}

extern "C" void kernel_launch(void* const* d_in, const int* in_sizes, int n_in,
                              void* d_out, int out_size, void* d_ws, size_t ws_size,
                              hipStream_t stream)
{
  const int*   sen  = (const int*)d_in[0];
  const float* emb  = (const float*)d_in[1];
  const float* W_ix = (const float*)d_in[2];  const float* b_ix = (const float*)d_in[3];
  const float* W_ih = (const float*)d_in[4];  const float* b_ih = (const float*)d_in[5];
  const float* W_fx = (const float*)d_in[6];  const float* b_fx = (const float*)d_in[7];
  const float* W_fh = (const float*)d_in[8];  const float* b_fh = (const float*)d_in[9];
  const float* W_ox = (const float*)d_in[10]; const float* b_ox = (const float*)d_in[11];
  const float* W_oh = (const float*)d_in[12]; const float* b_oh = (const float*)d_in[13];
  const float* W_ux = (const float*)d_in[14]; const float* b_ux = (const float*)d_in[15];
  const float* W_uh = (const float*)d_in[16]; const float* b_uh = (const float*)d_in[17];
  const float* W_out= (const float*)d_in[18]; const float* b_out= (const float*)d_in[19];
  float* out = (float*)d_out;

  // ---- workspace: arena A (L4/L2/L0 h+c), arena B (L3/L1 h+c), Ep, weights ----
  const size_t AH = (size_t)262144 * 128;   // u16 elems
  const size_t BH = (size_t)131072 * 128;
  const size_t EPB = (size_t)50000 * 512 * 2;
  const size_t need = 2 * AH * 2 + 2 * BH * 2 + EPB
                    + (size_t)512 * 128 * 2 + 4 * (size_t)128 * 128 * 2 + 512 * 4 + 8192;
  fprintf(stderr, "[tree_lstm] ws_size=%zu need=%zu\n", ws_size, need);
  if (ws_size < need) {
    fprintf(stderr, "[tree_lstm] INSUFFICIENT WORKSPACE — skipping launch\n");
    return;
  }
  char* ws = (char*)d_ws;
  size_t off = 0;
  auto take = [&](size_t bytes) { char* p = ws + off; off += (bytes + 255) & ~(size_t)255; return p; };
  u16* hA = (u16*)take(AH * 2);
  u16* cA = (u16*)take(AH * 2);
  u16* hB = (u16*)take(BH * 2);
  u16* cB = (u16*)take(BH * 2);
  u16* Ep = (u16*)take(EPB);
  u16* WallT = (u16*)take((size_t)512 * 128 * 2);
  u16* BihT = (u16*)take((size_t)128 * 128 * 2);
  u16* BuhT = (u16*)take((size_t)128 * 128 * 2);
  u16* BohT = (u16*)take((size_t)128 * 128 * 2);
  u16* BfhT = (u16*)take((size_t)128 * 128 * 2);
  float* bsum = (float*)take(512 * 4);

  // Leaf h/c vocab tables alias onto arena B: hB/cB are 33.5 MB each (>= 12.8 MB needed)
  // and are first written by L3, which launches only after L4 has consumed the tables.
  u16* Hl = hB;
  u16* Cl = cB;

  // ---- prep ----
  build_wallT<<<256, 256, 0, stream>>>(W_ix, W_ux, W_ox, W_fx, WallT);
  build_bsum<<<2, 256, 0, stream>>>(b_ix, b_ih, b_ux, b_uh, b_ox, b_oh, b_fx, b_fh, bsum);
  build_bt128<<<64, 256, 0, stream>>>(W_ih, BihT);
  build_bt128<<<64, 256, 0, stream>>>(W_uh, BuhT);
  build_bt128<<<64, 256, 0, stream>>>(W_oh, BohT);
  build_bt128<<<64, 256, 0, stream>>>(W_fh, BfhT);
  proj_e<<<391, 256, 0, stream>>>(emb, WallT, bsum, Ep);
  leaf_hc<<<12500, 256, 0, stream>>>(Ep, Hl, Cl);

  const long LOFF[6] = {0, 4096, 20480, 86016, 217088, 479232};

  // L4 (parents 262144, leaf children gathered from Hl/Cl tables) -> A
  k_level<0, true><<<4096, 256, 0, stream>>>(sen, Ep, Hl, Cl,
      BfhT, BihT, BuhT, BohT, cA, hA, LOFF[4], LOFF[5]);
  // L3 (131072, ratio 2) A -> B
  k_level<1, false><<<2048, 256, 0, stream>>>(sen, Ep, hA, cA,
      BfhT, BihT, BuhT, BohT, cB, hB, LOFF[3], 0);
  // L2 (65536, ratio 2) B -> A
  k_level<1, false><<<1024, 256, 0, stream>>>(sen, Ep, hB, cB,
      BfhT, BihT, BuhT, BohT, cA, hA, LOFF[2], 0);
  // L1 (16384, ratio 4) A -> B
  k_level<2, false><<<512, 256, 0, stream>>>(sen, Ep, hA, cA,
      BfhT, BihT, BuhT, BohT, cB, hB, LOFF[1], 0);
  // L0 (4096, ratio 4) B -> A
  k_level<2, false><<<128, 256, 0, stream>>>(sen, Ep, hB, cB,
      BfhT, BihT, BuhT, BohT, cA, hA, LOFF[0], 0);

  out_proj<<<64, 256, 0, stream>>>(hA, W_out, b_out, out);
}

// Round 2
// 599.777 us; speedup vs baseline: 1.0228x; 1.0019x over previous
//
#include <hip/hip_runtime.h>
#include <hip/hip_bf16.h>
#include <cstdio>

typedef unsigned short u16;
typedef __bf16 bf16x8 __attribute__((ext_vector_type(8)));
typedef float  floatx4 __attribute__((ext_vector_type(4)));

// ---------- scalar helpers ----------
__device__ __forceinline__ float bf2f(u16 u) {
  union { unsigned int i; float f; } v; v.i = ((unsigned int)u) << 16; return v.f;
}
__device__ __forceinline__ u16 f2bf(float f) {
  union { float f; unsigned int i; } v; v.f = f;
  unsigned int x = v.i;
  return (u16)((x + 0x7fffu + ((x >> 16) & 1u)) >> 16);   // RNE
}
__device__ __forceinline__ unsigned int f2bf_pk(float a, float b) {   // [lo=a, hi=b]
  __hip_bfloat162 h = __float22bfloat162_rn(make_float2(a, b));
  union { __hip_bfloat162 h; unsigned int u; } v; v.h = h; return v.u;
}
// fast gates: v_rcp (~1 ulp) + native exp — no IEEE div
__device__ __forceinline__ float sigmoidf_(float x) {
  return __builtin_amdgcn_rcpf(1.f + __expf(-x));
}
__device__ __forceinline__ float tanhf_(float x) {
  return fmaf(-2.f, __builtin_amdgcn_rcpf(1.f + __expf(2.f * x)), 1.f);
}

// LDS swizzle, 128-elem rows, 16B chunks: chunk' = chunk ^ (row&15)
__device__ __forceinline__ int swz128(int row, int c16) {
  return row * 128 + ((c16 ^ (row & 15)) << 3);
}
// element-level access into swizzled rows
__device__ __forceinline__ int swze(int row, int col) {
  return row * 128 + (((((col >> 3)) ^ (row & 15)) << 3) | (col & 7));
}

// ============ proj_e: Ep[v][col][4] = {i,u,o,f} pre-acts + biases (gate-interleaved) ============
__global__ __launch_bounds__(256, 2) void proj_e(
    const float* __restrict__ emb, const u16* __restrict__ WT,
    const float* __restrict__ bsum, u16* __restrict__ Ep)
{
  __shared__ __align__(16) u16 ldsA[128 * 128];
  const int tid = threadIdx.x;
  const long m0 = (long)blockIdx.x * 128;
  {
    const int r = tid >> 1, half = tid & 1;
    long row = m0 + r; if (row > 49999) row = 49999;
    const float* src = emb + row * 128 + half * 64;
#pragma unroll
    for (int i = 0; i < 8; i++) {
      float4 v0 = *reinterpret_cast<const float4*>(src + i * 8);
      float4 v1 = *reinterpret_cast<const float4*>(src + i * 8 + 4);
      unsigned int ov[4] = { f2bf_pk(v0.x, v0.y), f2bf_pk(v0.z, v0.w),
                             f2bf_pk(v1.x, v1.y), f2bf_pk(v1.z, v1.w) };
      *reinterpret_cast<uint4*>(&ldsA[swz128(r, half * 8 + i)]) =
          *reinterpret_cast<const uint4*>(ov);
    }
  }
  __syncthreads();
  const int lane = tid & 63, w = tid >> 6, l16 = lane & 15, quad = lane >> 4;
#pragma unroll
  for (int half = 0; half < 2; half++) {
    const int col = w * 32 + half * 16 + l16;
    bf16x8 bI[4], bU[4], bO[4], bF[4];
#pragma unroll
    for (int ks = 0; ks < 4; ks++) {
      const size_t o_ = ks * 32 + quad * 8;
      bI[ks] = *reinterpret_cast<const bf16x8*>(WT + (size_t)(0   + col) * 128 + o_);
      bU[ks] = *reinterpret_cast<const bf16x8*>(WT + (size_t)(128 + col) * 128 + o_);
      bO[ks] = *reinterpret_cast<const bf16x8*>(WT + (size_t)(256 + col) * 128 + o_);
      bF[ks] = *reinterpret_cast<const bf16x8*>(WT + (size_t)(384 + col) * 128 + o_);
    }
    const float bi = bsum[col], bu = bsum[128 + col], bo = bsum[256 + col], bf = bsum[384 + col];
#pragma unroll
    for (int i = 0; i < 8; i++) {
      floatx4 aI = {0.f,0.f,0.f,0.f}, aU = {0.f,0.f,0.f,0.f};
      floatx4 aO = {0.f,0.f,0.f,0.f}, aF = {0.f,0.f,0.f,0.f};
#pragma unroll
      for (int ks = 0; ks < 4; ks++) {
        bf16x8 a = *reinterpret_cast<const bf16x8*>(&ldsA[swz128(i * 16 + l16, ks * 4 + quad)]);
        aI = __builtin_amdgcn_mfma_f32_16x16x32_bf16(a, bI[ks], aI, 0, 0, 0);
        aU = __builtin_amdgcn_mfma_f32_16x16x32_bf16(a, bU[ks], aU, 0, 0, 0);
        aO = __builtin_amdgcn_mfma_f32_16x16x32_bf16(a, bO[ks], aO, 0, 0, 0);
        aF = __builtin_amdgcn_mfma_f32_16x16x32_bf16(a, bF[ks], aF, 0, 0, 0);
      }
#pragma unroll
      for (int r2 = 0; r2 < 4; r2++) {
        const long row = m0 + i * 16 + quad * 4 + r2;
        if (row < 50000) {
          u16 ov[4] = { f2bf(aI[r2] + bi), f2bf(aU[r2] + bu),
                        f2bf(aO[r2] + bo), f2bf(aF[r2] + bf) };
          *reinterpret_cast<ushort4*>(Ep + row * 512 + col * 4) =
              *reinterpret_cast<const ushort4*>(ov);
        }
      }
    }
  }
}

// ============ proj_h: Gh[v][col][4] = {i,u,o,f} h-side pre-acts = Hl[v] @ W_*h (NO bias) ============
__global__ __launch_bounds__(256, 2) void proj_h(
    const u16* __restrict__ Hl,
    const u16* __restrict__ BihT, const u16* __restrict__ BuhT,
    const u16* __restrict__ BohT, const u16* __restrict__ BfT,
    u16* __restrict__ Gh)
{
  __shared__ __align__(16) u16 ldsA[128 * 128];
  const int tid = threadIdx.x;
  const long m0 = (long)blockIdx.x * 128;
  {
    const int r = tid >> 1, half = tid & 1;
    long row = m0 + r; if (row > 49999) row = 49999;
    const u16* src = Hl + row * 128 + half * 64;
#pragma unroll
    for (int i = 0; i < 8; i++)
      *reinterpret_cast<uint4*>(&ldsA[swz128(r, half * 8 + i)]) =
          *reinterpret_cast<const uint4*>(src + i * 8);
  }
  __syncthreads();
  const int lane = tid & 63, w = tid >> 6, l16 = lane & 15, quad = lane >> 4;
#pragma unroll
  for (int half = 0; half < 2; half++) {
    const int col = w * 32 + half * 16 + l16;
    bf16x8 bI[4], bU[4], bO[4], bF[4];
#pragma unroll
    for (int ks = 0; ks < 4; ks++) {
      const size_t o_ = (size_t)col * 128 + ks * 32 + quad * 8;
      bI[ks] = *reinterpret_cast<const bf16x8*>(BihT + o_);
      bU[ks] = *reinterpret_cast<const bf16x8*>(BuhT + o_);
      bO[ks] = *reinterpret_cast<const bf16x8*>(BohT + o_);
      bF[ks] = *reinterpret_cast<const bf16x8*>(BfT  + o_);
    }
#pragma unroll
    for (int i = 0; i < 8; i++) {
      floatx4 aI = {0.f,0.f,0.f,0.f}, aU = {0.f,0.f,0.f,0.f};
      floatx4 aO = {0.f,0.f,0.f,0.f}, aF = {0.f,0.f,0.f,0.f};
#pragma unroll
      for (int ks = 0; ks < 4; ks++) {
        bf16x8 a = *reinterpret_cast<const bf16x8*>(&ldsA[swz128(i * 16 + l16, ks * 4 + quad)]);
        aI = __builtin_amdgcn_mfma_f32_16x16x32_bf16(a, bI[ks], aI, 0, 0, 0);
        aU = __builtin_amdgcn_mfma_f32_16x16x32_bf16(a, bU[ks], aU, 0, 0, 0);
        aO = __builtin_amdgcn_mfma_f32_16x16x32_bf16(a, bO[ks], aO, 0, 0, 0);
        aF = __builtin_amdgcn_mfma_f32_16x16x32_bf16(a, bF[ks], aF, 0, 0, 0);
      }
#pragma unroll
      for (int r2 = 0; r2 < 4; r2++) {
        const long row = m0 + i * 16 + quad * 4 + r2;
        if (row < 50000) {
          u16 ov[4] = { f2bf(aI[r2]), f2bf(aU[r2]), f2bf(aO[r2]), f2bf(aF[r2]) };
          *reinterpret_cast<ushort4*>(Gh + row * 512 + col * 4) =
              *reinterpret_cast<const ushort4*>(ov);
        }
      }
    }
  }
}

// ============ leaf_hc: vocab-level leaf activations Hl[v][128], Cl[v][128] ============
__global__ void leaf_hc(const u16* __restrict__ Ep,
                        u16* __restrict__ Hl, u16* __restrict__ Cl)
{
  const int tid = threadIdx.x;
  const int r = tid >> 6, c2 = tid & 63;           // 4 vocab rows/block, 2 cols/thread
  const size_t v = (size_t)blockIdx.x * 4 + r;     // grid = 12500 -> covers 50000 exactly
  uint4 g = *reinterpret_cast<const uint4*>(Ep + v * 512 + (size_t)c2 * 8);
  const u16* p = reinterpret_cast<const u16*>(&g); // {i,u,o,f} x 2 cols
  float c0 = sigmoidf_(bf2f(p[0])) * tanhf_(bf2f(p[1]));
  float c1 = sigmoidf_(bf2f(p[4])) * tanhf_(bf2f(p[5]));
  float h0 = sigmoidf_(bf2f(p[2])) * tanhf_(c0);
  float h1 = sigmoidf_(bf2f(p[6])) * tanhf_(c1);
  *reinterpret_cast<unsigned int*>(Hl + v * 128 + c2 * 2) = f2bf_pk(h0, h1);
  *reinterpret_cast<unsigned int*>(Cl + v * 128 + c2 * 2) = f2bf_pk(c0, c1);
}

// ============ l4_leaf: ratio-1 level as pure elementwise gather (no MFMA/LDS/barrier) ============
// Per parent p: vp = parent vocab id, vc = child vocab id.
// gates = act(Ep[vp] + Gh[vc]); c = i*u + f*Cl[vc]; h = o*tanh(c).
// One wave per parent: 16B/lane coalesced row reads, 4B/lane coalesced stores.
__global__ __launch_bounds__(256) void l4_leaf(
    const int* __restrict__ sen, const u16* __restrict__ Ep,
    const u16* __restrict__ Gh, const u16* __restrict__ Cl,
    u16* __restrict__ c_out, u16* __restrict__ h_out,
    long o0, long co0)
{
  const int lane = threadIdx.x & 63, w = threadIdx.x >> 6;
  const long p = (long)blockIdx.x * 4 + w;
  const size_t vp = (size_t)sen[o0 + p];
  const size_t vc = (size_t)sen[co0 + p];
  uint4 e = *reinterpret_cast<const uint4*>(Ep + vp * 512 + (size_t)lane * 8);
  uint4 g = *reinterpret_cast<const uint4*>(Gh + vc * 512 + (size_t)lane * 8);
  unsigned int cl2 = *reinterpret_cast<const unsigned int*>(Cl + vc * 128 + (size_t)lane * 2);
  const u16* ep = reinterpret_cast<const u16*>(&e);
  const u16* gp = reinterpret_cast<const u16*>(&g);
  const float cl0 = bf2f((u16)(cl2 & 0xffffu)), cl1 = bf2f((u16)(cl2 >> 16));
  const float i0 = sigmoidf_(bf2f(ep[0]) + bf2f(gp[0]));
  const float u0 = tanhf_   (bf2f(ep[1]) + bf2f(gp[1]));
  const float o0g= sigmoidf_(bf2f(ep[2]) + bf2f(gp[2]));
  const float f0 = sigmoidf_(bf2f(ep[3]) + bf2f(gp[3]));
  const float i1 = sigmoidf_(bf2f(ep[4]) + bf2f(gp[4]));
  const float u1 = tanhf_   (bf2f(ep[5]) + bf2f(gp[5]));
  const float o1g= sigmoidf_(bf2f(ep[6]) + bf2f(gp[6]));
  const float f1 = sigmoidf_(bf2f(ep[7]) + bf2f(gp[7]));
  const float c0 = fmaf(i0, u0, f0 * cl0);
  const float c1 = fmaf(i1, u1, f1 * cl1);
  const float h0 = o0g * tanhf_(c0);
  const float h1 = o1g * tanhf_(c1);
  *reinterpret_cast<unsigned int*>(c_out + p * 128 + lane * 2) = f2bf_pk(c0, c1);
  *reinterpret_cast<unsigned int*>(h_out + p * 128 + lane * 2) = f2bf_pk(h0, h1);
}

// ============ k_level: per-i-tile fused f/i/u/o (levels with ratio >= 1 and computed children) ======
template<int LR, bool LEAF>
__global__ __launch_bounds__(256, 2) void k_level(
    const int* __restrict__ sen, const u16* __restrict__ Ep,
    const u16* __restrict__ h_prev, const u16* __restrict__ c_prev,
    const u16* __restrict__ BfT, const u16* __restrict__ BihT,
    const u16* __restrict__ BuhT, const u16* __restrict__ BohT,
    u16* __restrict__ c_out, u16* __restrict__ h_out,
    long o0, long co0)
{
  constexpr int PM  = (LR == 2) ? 32 : 64;
  constexpr int CM  = PM << LR;
  constexpr int NCI = CM / 16;
  constexpr int RT  = 1 << LR;
  constexpr int RTI = 4 >> LR;         // parents per 4-row quad block
  constexpr int TPR = 256 / CM;        // staging threads per child row
  __shared__ __align__(16) u16 ldsA[CM * 128];            // child h (swz)
  __shared__ __align__(16) u16 ldsC[LEAF ? CM * 128 : 8]; // LEAF: child c (swz)
  __shared__ int sidP[PM];

  const int tid = threadIdx.x;
  const long p0 = (long)blockIdx.x * PM;
  const long cb = (long)blockIdx.x * CM;

  // ---- stage children ----
  {
    const int r = tid / TPR, q = tid % TPR;
    constexpr int CH = 16 / TPR;
    if (LEAF) {
      const size_t v = (size_t)sen[co0 + cb + r];
      const u16* hs = h_prev + v * 128;
      const u16* cs = c_prev + v * 128;
#pragma unroll
      for (int ii = 0; ii < CH; ii++) {
        const int c16 = q * CH + ii;
        *reinterpret_cast<uint4*>(&ldsA[swz128(r, c16)]) =
            *reinterpret_cast<const uint4*>(hs + c16 * 8);
        *reinterpret_cast<uint4*>(&ldsC[swz128(r, c16)]) =
            *reinterpret_cast<const uint4*>(cs + c16 * 8);
      }
    } else {
      const u16* src = h_prev + (cb + r) * 128;
#pragma unroll
      for (int ii = 0; ii < CH; ii++) {
        const int c16 = q * CH + ii;
        *reinterpret_cast<uint4*>(&ldsA[swz128(r, c16)]) =
            *reinterpret_cast<const uint4*>(src + c16 * 8);
      }
    }
    if (tid < PM) sidP[tid] = sen[o0 + p0 + tid];
  }
  __syncthreads();

  const int lane = tid & 63, w = tid >> 6, l16 = lane & 15, quad = lane >> 4;

#pragma unroll
  for (int gl = 0; gl < 2; gl++) {
    const int col = w * 32 + gl * 16 + l16;
    bf16x8 bF[4], bI[4], bU[4], bO[4];
#pragma unroll
    for (int ks = 0; ks < 4; ks++) {
      const size_t bo_ = (size_t)col * 128 + ks * 32 + quad * 8;
      bF[ks] = *reinterpret_cast<const bf16x8*>(BfT + bo_);
      bI[ks] = *reinterpret_cast<const bf16x8*>(BihT + bo_);
      bU[ks] = *reinterpret_cast<const bf16x8*>(BuhT + bo_);
      bO[ks] = *reinterpret_cast<const bf16x8*>(BohT + bo_);
    }
#pragma unroll
    for (int i = 0; i < NCI; i++) {
      floatx4 aF = {0.f,0.f,0.f,0.f}, aI = {0.f,0.f,0.f,0.f};
      floatx4 aU = {0.f,0.f,0.f,0.f}, aO = {0.f,0.f,0.f,0.f};
#pragma unroll
      for (int ks = 0; ks < 4; ks++) {
        bf16x8 a = *reinterpret_cast<const bf16x8*>(&ldsA[swz128(i * 16 + l16, ks * 4 + quad)]);
        aF = __builtin_amdgcn_mfma_f32_16x16x32_bf16(a, bF[ks], aF, 0, 0, 0);
        aI = __builtin_amdgcn_mfma_f32_16x16x32_bf16(a, bI[ks], aI, 0, 0, 0);
        aU = __builtin_amdgcn_mfma_f32_16x16x32_bf16(a, bU[ks], aU, 0, 0, 0);
        aO = __builtin_amdgcn_mfma_f32_16x16x32_bf16(a, bO[ks], aO, 0, 0, 0);
      }
      const int rbase = i * 16 + quad * 4;
#pragma unroll
      for (int t = 0; t < RTI; t++) {
        const int p = (rbase >> LR) + t;
        ushort4 g4 = *reinterpret_cast<const ushort4*>(Ep + (size_t)sidP[p] * 512 + col * 4);
        const float epf = bf2f(g4.w);
        float fsum = 0.f, isum = 0.f, usum = 0.f, osum = 0.f;
#pragma unroll
        for (int r2 = t * RT; r2 < t * RT + RT; r2++) {
          const int row = rbase + r2;
          const float cch = LEAF ? bf2f(ldsC[swze(row, col)])
                                 : bf2f(c_prev[(cb + row) * 128 + col]);
          fsum += sigmoidf_(aF[r2] + epf) * cch;
          isum += aI[r2]; usum += aU[r2]; osum += aO[r2];
        }
        const float c = sigmoidf_(isum + bf2f(g4.x)) * tanhf_(usum + bf2f(g4.y)) + fsum;
        const float h = sigmoidf_(osum + bf2f(g4.z)) * tanhf_(c);
        c_out[(p0 + p) * 128 + col] = f2bf(c);
        h_out[(p0 + p) * 128 + col] = f2bf(h);
      }
    }
  }
}

// ---------- weight/bias prep ----------
__global__ void build_wallT(const float* __restrict__ Wix, const float* __restrict__ Wux,
                            const float* __restrict__ Wox, const float* __restrict__ Wfx,
                            u16* __restrict__ WT)
{
  int idx = blockIdx.x * 256 + threadIdx.x;   // 512*128
  int n = idx >> 7, k = idx & 127;
  int g = n >> 7, j = n & 127;
  const float* W = (g == 0) ? Wix : (g == 1) ? Wux : (g == 2) ? Wox : Wfx;
  WT[idx] = f2bf(W[k * 128 + j]);
}

__global__ void build_bsum(const float* __restrict__ b_ix, const float* __restrict__ b_ih,
                           const float* __restrict__ b_ux, const float* __restrict__ b_uh,
                           const float* __restrict__ b_ox, const float* __restrict__ b_oh,
                           const float* __restrict__ b_fx, const float* __restrict__ b_fh,
                           float* __restrict__ bsum)
{
  int n = blockIdx.x * 256 + threadIdx.x;   // 512
  int g = n >> 7, j = n & 127;
  float v = (g == 0) ? b_ix[j] + b_ih[j] : (g == 1) ? b_ux[j] + b_uh[j]
          : (g == 2) ? b_ox[j] + b_oh[j] : b_fx[j] + b_fh[j];
  bsum[n] = v;
}

__global__ void build_bt128(const float* __restrict__ W, u16* __restrict__ BT) {
  int idx = blockIdx.x * 256 + threadIdx.x;   // 128*128
  int n = idx >> 7, k = idx & 127;
  BT[idx] = f2bf(W[k * 128 + n]);
}

// ---------- output projection (4096 x 4, tiny) ----------
__global__ void out_proj(const u16* __restrict__ h_root, const float* __restrict__ W_out,
                         const float* __restrict__ b_out, float* __restrict__ out)
{
  int idx = blockIdx.x * 256 + threadIdx.x;   // 4096*4
  int n = idx >> 2, cls = idx & 3;
  float s = b_out[cls];
  for (int k = 0; k < 128; k++)
    s += bf2f(h_root[(long)n * 128 + k]) * W_out[k * 4 + cls];
  out[idx] = s;
}

extern "C" void kernel_launch(void* const* d_in, const int* in_sizes, int n_in,
                              void* d_out, int out_size, void* d_ws, size_t ws_size,
                              hipStream_t stream)
{
  const int*   sen  = (const int*)d_in[0];
  const float* emb  = (const float*)d_in[1];
  const float* W_ix = (const float*)d_in[2];  const float* b_ix = (const float*)d_in[3];
  const float* W_ih = (const float*)d_in[4];  const float* b_ih = (const float*)d_in[5];
  const float* W_fx = (const float*)d_in[6];  const float* b_fx = (const float*)d_in[7];
  const float* W_fh = (const float*)d_in[8];  const float* b_fh = (const float*)d_in[9];
  const float* W_ox = (const float*)d_in[10]; const float* b_ox = (const float*)d_in[11];
  const float* W_oh = (const float*)d_in[12]; const float* b_oh = (const float*)d_in[13];
  const float* W_ux = (const float*)d_in[14]; const float* b_ux = (const float*)d_in[15];
  const float* W_uh = (const float*)d_in[16]; const float* b_uh = (const float*)d_in[17];
  const float* W_out= (const float*)d_in[18]; const float* b_out= (const float*)d_in[19];
  float* out = (float*)d_out;

  // ---- workspace: arena A (L4/L2/L0 h+c), arena B (L3/L1 h+c), Ep, Gh, weights ----
  const size_t AH = (size_t)262144 * 128;   // u16 elems
  const size_t BH = (size_t)131072 * 128;
  const size_t EPB = (size_t)50000 * 512 * 2;
  const size_t need_base = 2 * AH * 2 + 2 * BH * 2 + EPB
                    + (size_t)512 * 128 * 2 + 4 * (size_t)128 * 128 * 2 + 512 * 4 + 8192;
  const size_t need_full = need_base + EPB + 256;   // + Gh table
  fprintf(stderr, "[tree_lstm] ws_size=%zu need_base=%zu need_full=%zu\n",
          ws_size, need_base, need_full);
  if (ws_size < need_base) {
    fprintf(stderr, "[tree_lstm] INSUFFICIENT WORKSPACE — skipping launch\n");
    return;
  }
  const bool useGh = (ws_size >= need_full);
  char* ws = (char*)d_ws;
  size_t off = 0;
  auto take = [&](size_t bytes) { char* p = ws + off; off += (bytes + 255) & ~(size_t)255; return p; };
  u16* hA = (u16*)take(AH * 2);
  u16* cA = (u16*)take(AH * 2);
  u16* hB = (u16*)take(BH * 2);
  u16* cB = (u16*)take(BH * 2);
  u16* Ep = (u16*)take(EPB);
  u16* WallT = (u16*)take((size_t)512 * 128 * 2);
  u16* BihT = (u16*)take((size_t)128 * 128 * 2);
  u16* BuhT = (u16*)take((size_t)128 * 128 * 2);
  u16* BohT = (u16*)take((size_t)128 * 128 * 2);
  u16* BfhT = (u16*)take((size_t)128 * 128 * 2);
  float* bsum = (float*)take(512 * 4);
  u16* Gh = useGh ? (u16*)take(EPB) : nullptr;

  // Leaf h/c vocab tables alias onto arena B (dead until L3 writes it, after L4).
  u16* Hl = hB;
  u16* Cl = cB;

  // ---- prep ----
  build_wallT<<<256, 256, 0, stream>>>(W_ix, W_ux, W_ox, W_fx, WallT);
  build_bsum<<<2, 256, 0, stream>>>(b_ix, b_ih, b_ux, b_uh, b_ox, b_oh, b_fx, b_fh, bsum);
  build_bt128<<<64, 256, 0, stream>>>(W_ih, BihT);
  build_bt128<<<64, 256, 0, stream>>>(W_uh, BuhT);
  build_bt128<<<64, 256, 0, stream>>>(W_oh, BohT);
  build_bt128<<<64, 256, 0, stream>>>(W_fh, BfhT);
  proj_e<<<391, 256, 0, stream>>>(emb, WallT, bsum, Ep);
  leaf_hc<<<12500, 256, 0, stream>>>(Ep, Hl, Cl);

  const long LOFF[6] = {0, 4096, 20480, 86016, 217088, 479232};

  // L4 (parents 262144, ratio 1): elementwise gather via vocab-space Gh table
  if (useGh) {
    proj_h<<<391, 256, 0, stream>>>(Hl, BihT, BuhT, BohT, BfhT, Gh);
    l4_leaf<<<65536, 256, 0, stream>>>(sen, Ep, Gh, Cl, cA, hA, LOFF[4], LOFF[5]);
  } else {
    k_level<0, true><<<4096, 256, 0, stream>>>(sen, Ep, Hl, Cl,
        BfhT, BihT, BuhT, BohT, cA, hA, LOFF[4], LOFF[5]);
  }
  // L3 (131072, ratio 2) A -> B
  k_level<1, false><<<2048, 256, 0, stream>>>(sen, Ep, hA, cA,
      BfhT, BihT, BuhT, BohT, cB, hB, LOFF[3], 0);
  // L2 (65536, ratio 2) B -> A
  k_level<1, false><<<1024, 256, 0, stream>>>(sen, Ep, hB, cB,
      BfhT, BihT, BuhT, BohT, cA, hA, LOFF[2], 0);
  // L1 (16384, ratio 4) A -> B
  k_level<2, false><<<512, 256, 0, stream>>>(sen, Ep, hA, cA,
      BfhT, BihT, BuhT, BohT, cB, hB, LOFF[1], 0);
  // L0 (4096, ratio 4) B -> A
  k_level<2, false><<<128, 256, 0, stream>>>(sen, Ep, hB, cB,
      BfhT, BihT, BuhT, BohT, cA, hA, LOFF[0], 0);

  out_proj<<<64, 256, 0, stream>>>(hA, W_out, b_out, out);
}

// Round 3
// 541.477 us; speedup vs baseline: 1.1329x; 1.1077x over previous
//
#include <hip/hip_runtime.h>
#include <hip/hip_bf16.h>
#include <cstdio>

typedef unsigned short u16;
typedef __bf16 bf16x8 __attribute__((ext_vector_type(8)));
typedef float  floatx4 __attribute__((ext_vector_type(4)));

// ---------- scalar helpers ----------
__device__ __forceinline__ float bf2f(u16 u) {
  union { unsigned int i; float f; } v; v.i = ((unsigned int)u) << 16; return v.f;
}
__device__ __forceinline__ u16 f2bf(float f) {
  union { float f; unsigned int i; } v; v.f = f;
  unsigned int x = v.i;
  return (u16)((x + 0x7fffu + ((x >> 16) & 1u)) >> 16);   // RNE
}
__device__ __forceinline__ unsigned int f2bf_pk(float a, float b) {   // [lo=a, hi=b]
  __hip_bfloat162 h = __float22bfloat162_rn(make_float2(a, b));
  union { __hip_bfloat162 h; unsigned int u; } v; v.h = h; return v.u;
}
// fast gates: v_rcp (~1 ulp) + native exp — no IEEE div
__device__ __forceinline__ float sigmoidf_(float x) {
  return __builtin_amdgcn_rcpf(1.f + __expf(-x));
}
__device__ __forceinline__ float tanhf_(float x) {
  return fmaf(-2.f, __builtin_amdgcn_rcpf(1.f + __expf(2.f * x)), 1.f);
}

// LDS swizzle, 128-elem rows, 16B chunks: chunk' = chunk ^ (row&15)
__device__ __forceinline__ int swz128(int row, int c16) {
  return row * 128 + ((c16 ^ (row & 15)) << 3);
}
// element-level access into swizzled rows
__device__ __forceinline__ int swze(int row, int col) {
  return row * 128 + (((((col >> 3)) ^ (row & 15)) << 3) | (col & 7));
}

// ============ proj_e: Ep[v][col][4] = {i,u,o,f} pre-acts + biases (gate-interleaved) ============
__global__ __launch_bounds__(256, 2) void proj_e(
    const float* __restrict__ emb, const u16* __restrict__ WT,
    const float* __restrict__ bsum, u16* __restrict__ Ep)
{
  __shared__ __align__(16) u16 ldsA[128 * 128];
  const int tid = threadIdx.x;
  const long m0 = (long)blockIdx.x * 128;
  {
    const int r = tid >> 1, half = tid & 1;
    long row = m0 + r; if (row > 49999) row = 49999;
    const float* src = emb + row * 128 + half * 64;
#pragma unroll
    for (int i = 0; i < 8; i++) {
      float4 v0 = *reinterpret_cast<const float4*>(src + i * 8);
      float4 v1 = *reinterpret_cast<const float4*>(src + i * 8 + 4);
      unsigned int ov[4] = { f2bf_pk(v0.x, v0.y), f2bf_pk(v0.z, v0.w),
                             f2bf_pk(v1.x, v1.y), f2bf_pk(v1.z, v1.w) };
      *reinterpret_cast<uint4*>(&ldsA[swz128(r, half * 8 + i)]) =
          *reinterpret_cast<const uint4*>(ov);
    }
  }
  __syncthreads();
  const int lane = tid & 63, w = tid >> 6, l16 = lane & 15, quad = lane >> 4;
#pragma unroll
  for (int half = 0; half < 2; half++) {
    const int col = w * 32 + half * 16 + l16;
    bf16x8 bI[4], bU[4], bO[4], bF[4];
#pragma unroll
    for (int ks = 0; ks < 4; ks++) {
      const size_t o_ = ks * 32 + quad * 8;
      bI[ks] = *reinterpret_cast<const bf16x8*>(WT + (size_t)(0   + col) * 128 + o_);
      bU[ks] = *reinterpret_cast<const bf16x8*>(WT + (size_t)(128 + col) * 128 + o_);
      bO[ks] = *reinterpret_cast<const bf16x8*>(WT + (size_t)(256 + col) * 128 + o_);
      bF[ks] = *reinterpret_cast<const bf16x8*>(WT + (size_t)(384 + col) * 128 + o_);
    }
    const float bi = bsum[col], bu = bsum[128 + col], bo = bsum[256 + col], bf = bsum[384 + col];
#pragma unroll
    for (int i = 0; i < 8; i++) {
      floatx4 aI = {0.f,0.f,0.f,0.f}, aU = {0.f,0.f,0.f,0.f};
      floatx4 aO = {0.f,0.f,0.f,0.f}, aF = {0.f,0.f,0.f,0.f};
#pragma unroll
      for (int ks = 0; ks < 4; ks++) {
        bf16x8 a = *reinterpret_cast<const bf16x8*>(&ldsA[swz128(i * 16 + l16, ks * 4 + quad)]);
        aI = __builtin_amdgcn_mfma_f32_16x16x32_bf16(a, bI[ks], aI, 0, 0, 0);
        aU = __builtin_amdgcn_mfma_f32_16x16x32_bf16(a, bU[ks], aU, 0, 0, 0);
        aO = __builtin_amdgcn_mfma_f32_16x16x32_bf16(a, bO[ks], aO, 0, 0, 0);
        aF = __builtin_amdgcn_mfma_f32_16x16x32_bf16(a, bF[ks], aF, 0, 0, 0);
      }
#pragma unroll
      for (int r2 = 0; r2 < 4; r2++) {
        const long row = m0 + i * 16 + quad * 4 + r2;
        if (row < 50000) {
          u16 ov[4] = { f2bf(aI[r2] + bi), f2bf(aU[r2] + bu),
                        f2bf(aO[r2] + bo), f2bf(aF[r2] + bf) };
          *reinterpret_cast<ushort4*>(Ep + row * 512 + col * 4) =
              *reinterpret_cast<const ushort4*>(ov);
        }
      }
    }
  }
}

// ============ proj_hc: fused leaf activations + h-side projection ============
// Staging: Ep[v] -> leaf h (LDS, swizzled) and leaf c -> Cl[v] (global).
// MFMA:    Gh[v][col][4] = {i,u,o,f} h-side pre-acts = Hleaf[v] @ W_*h (no bias).
__global__ __launch_bounds__(256, 2) void proj_hc(
    const u16* __restrict__ Ep,
    const u16* __restrict__ BihT, const u16* __restrict__ BuhT,
    const u16* __restrict__ BohT, const u16* __restrict__ BfT,
    u16* __restrict__ Cl, u16* __restrict__ Gh)
{
  __shared__ __align__(16) u16 ldsA[128 * 128];
  const int tid = threadIdx.x;
  const long m0 = (long)blockIdx.x * 128;
  {
    const int r = tid >> 1, half = tid & 1;
    long row = m0 + r;
    const bool ok = (row < 50000); if (!ok) row = 49999;
    const u16* src = Ep + row * 512 + half * 256;
#pragma unroll
    for (int i = 0; i < 8; i++) {
      uint4 v[4];
#pragma unroll
      for (int k = 0; k < 4; k++)
        v[k] = *reinterpret_cast<const uint4*>(src + i * 32 + k * 8);
      unsigned int hp[4], cp[4];
#pragma unroll
      for (int k = 0; k < 4; k++) {      // each uint4 = 2 cols x {i,u,o,f}
        const u16* p = reinterpret_cast<const u16*>(&v[k]);
        float c0 = sigmoidf_(bf2f(p[0])) * tanhf_(bf2f(p[1]));
        float c1 = sigmoidf_(bf2f(p[4])) * tanhf_(bf2f(p[5]));
        float h0 = sigmoidf_(bf2f(p[2])) * tanhf_(c0);
        float h1 = sigmoidf_(bf2f(p[6])) * tanhf_(c1);
        cp[k] = f2bf_pk(c0, c1);
        hp[k] = f2bf_pk(h0, h1);
      }
      *reinterpret_cast<uint4*>(&ldsA[swz128(r, half * 8 + i)]) =
          *reinterpret_cast<const uint4*>(hp);
      if (ok)
        *reinterpret_cast<uint4*>(Cl + row * 128 + half * 64 + i * 8) =
            *reinterpret_cast<const uint4*>(cp);
    }
  }
  __syncthreads();
  const int lane = tid & 63, w = tid >> 6, l16 = lane & 15, quad = lane >> 4;
#pragma unroll
  for (int half = 0; half < 2; half++) {
    const int col = w * 32 + half * 16 + l16;
    bf16x8 bI[4], bU[4], bO[4], bF[4];
#pragma unroll
    for (int ks = 0; ks < 4; ks++) {
      const size_t o_ = (size_t)col * 128 + ks * 32 + quad * 8;
      bI[ks] = *reinterpret_cast<const bf16x8*>(BihT + o_);
      bU[ks] = *reinterpret_cast<const bf16x8*>(BuhT + o_);
      bO[ks] = *reinterpret_cast<const bf16x8*>(BohT + o_);
      bF[ks] = *reinterpret_cast<const bf16x8*>(BfT  + o_);
    }
#pragma unroll
    for (int i = 0; i < 8; i++) {
      floatx4 aI = {0.f,0.f,0.f,0.f}, aU = {0.f,0.f,0.f,0.f};
      floatx4 aO = {0.f,0.f,0.f,0.f}, aF = {0.f,0.f,0.f,0.f};
#pragma unroll
      for (int ks = 0; ks < 4; ks++) {
        bf16x8 a = *reinterpret_cast<const bf16x8*>(&ldsA[swz128(i * 16 + l16, ks * 4 + quad)]);
        aI = __builtin_amdgcn_mfma_f32_16x16x32_bf16(a, bI[ks], aI, 0, 0, 0);
        aU = __builtin_amdgcn_mfma_f32_16x16x32_bf16(a, bU[ks], aU, 0, 0, 0);
        aO = __builtin_amdgcn_mfma_f32_16x16x32_bf16(a, bO[ks], aO, 0, 0, 0);
        aF = __builtin_amdgcn_mfma_f32_16x16x32_bf16(a, bF[ks], aF, 0, 0, 0);
      }
#pragma unroll
      for (int r2 = 0; r2 < 4; r2++) {
        const long row = m0 + i * 16 + quad * 4 + r2;
        if (row < 50000) {
          u16 ov[4] = { f2bf(aI[r2]), f2bf(aU[r2]), f2bf(aO[r2]), f2bf(aF[r2]) };
          *reinterpret_cast<ushort4*>(Gh + row * 512 + col * 4) =
              *reinterpret_cast<const ushort4*>(ov);
        }
      }
    }
  }
}

// ============ l4_leaf: ratio-1 level as pure elementwise gather (no MFMA/LDS/barrier) ============
// Per parent p: vp = parent vocab id, vc = child vocab id.
// gates = act(Ep[vp] + Gh[vc]); c = i*u + f*Cl[vc]; h = o*tanh(c).
__global__ __launch_bounds__(256) void l4_leaf(
    const int* __restrict__ sen, const u16* __restrict__ Ep,
    const u16* __restrict__ Gh, const u16* __restrict__ Cl,
    u16* __restrict__ c_out, u16* __restrict__ h_out,
    long o0, long co0)
{
  const int lane = threadIdx.x & 63, w = threadIdx.x >> 6;
  const long p = (long)blockIdx.x * 4 + w;
  const size_t vp = (size_t)sen[o0 + p];
  const size_t vc = (size_t)sen[co0 + p];
  uint4 e = *reinterpret_cast<const uint4*>(Ep + vp * 512 + (size_t)lane * 8);
  uint4 g = *reinterpret_cast<const uint4*>(Gh + vc * 512 + (size_t)lane * 8);
  unsigned int cl2 = *reinterpret_cast<const unsigned int*>(Cl + vc * 128 + (size_t)lane * 2);
  const u16* ep = reinterpret_cast<const u16*>(&e);
  const u16* gp = reinterpret_cast<const u16*>(&g);
  const float cl0 = bf2f((u16)(cl2 & 0xffffu)), cl1 = bf2f((u16)(cl2 >> 16));
  const float i0 = sigmoidf_(bf2f(ep[0]) + bf2f(gp[0]));
  const float u0 = tanhf_   (bf2f(ep[1]) + bf2f(gp[1]));
  const float o0g= sigmoidf_(bf2f(ep[2]) + bf2f(gp[2]));
  const float f0 = sigmoidf_(bf2f(ep[3]) + bf2f(gp[3]));
  const float i1 = sigmoidf_(bf2f(ep[4]) + bf2f(gp[4]));
  const float u1 = tanhf_   (bf2f(ep[5]) + bf2f(gp[5]));
  const float o1g= sigmoidf_(bf2f(ep[6]) + bf2f(gp[6]));
  const float f1 = sigmoidf_(bf2f(ep[7]) + bf2f(gp[7]));
  const float c0 = fmaf(i0, u0, f0 * cl0);
  const float c1 = fmaf(i1, u1, f1 * cl1);
  const float h0 = o0g * tanhf_(c0);
  const float h1 = o1g * tanhf_(c1);
  *reinterpret_cast<unsigned int*>(c_out + p * 128 + lane * 2) = f2bf_pk(c0, c1);
  *reinterpret_cast<unsigned int*>(h_out + p * 128 + lane * 2) = f2bf_pk(h0, h1);
}

// ============ k_level: per-i-tile fused f/i/u/o (inner levels, computed children) ============
template<int LR, bool LEAF>
__global__ __launch_bounds__(256, 2) void k_level(
    const int* __restrict__ sen, const u16* __restrict__ Ep,
    const u16* __restrict__ h_prev, const u16* __restrict__ c_prev,
    const u16* __restrict__ BfT, const u16* __restrict__ BihT,
    const u16* __restrict__ BuhT, const u16* __restrict__ BohT,
    u16* __restrict__ c_out, u16* __restrict__ h_out,
    long o0, long co0)
{
  constexpr int PM  = (LR == 2) ? 32 : 64;
  constexpr int CM  = PM << LR;
  constexpr int NCI = CM / 16;
  constexpr int RT  = 1 << LR;
  constexpr int RTI = 4 >> LR;         // parents per 4-row quad block
  constexpr int TPR = 256 / CM;        // staging threads per child row
  __shared__ __align__(16) u16 ldsA[CM * 128];            // child h (swz)
  __shared__ __align__(16) u16 ldsC[LEAF ? CM * 128 : 8]; // LEAF: child c (swz)
  __shared__ int sidP[PM];

  const int tid = threadIdx.x;
  const long p0 = (long)blockIdx.x * PM;
  const long cb = (long)blockIdx.x * CM;

  // ---- stage children ----
  {
    const int r = tid / TPR, q = tid % TPR;
    constexpr int CH = 16 / TPR;
    if (LEAF) {
      const size_t v = (size_t)sen[co0 + cb + r];
      const u16* hs = h_prev + v * 128;
      const u16* cs = c_prev + v * 128;
#pragma unroll
      for (int ii = 0; ii < CH; ii++) {
        const int c16 = q * CH + ii;
        *reinterpret_cast<uint4*>(&ldsA[swz128(r, c16)]) =
            *reinterpret_cast<const uint4*>(hs + c16 * 8);
        *reinterpret_cast<uint4*>(&ldsC[swz128(r, c16)]) =
            *reinterpret_cast<const uint4*>(cs + c16 * 8);
      }
    } else {
      const u16* src = h_prev + (cb + r) * 128;
#pragma unroll
      for (int ii = 0; ii < CH; ii++) {
        const int c16 = q * CH + ii;
        *reinterpret_cast<uint4*>(&ldsA[swz128(r, c16)]) =
            *reinterpret_cast<const uint4*>(src + c16 * 8);
      }
    }
    if (tid < PM) sidP[tid] = sen[o0 + p0 + tid];
  }
  __syncthreads();

  const int lane = tid & 63, w = tid >> 6, l16 = lane & 15, quad = lane >> 4;

#pragma unroll
  for (int gl = 0; gl < 2; gl++) {
    const int col = w * 32 + gl * 16 + l16;
    bf16x8 bF[4], bI[4], bU[4], bO[4];
#pragma unroll
    for (int ks = 0; ks < 4; ks++) {
      const size_t bo_ = (size_t)col * 128 + ks * 32 + quad * 8;
      bF[ks] = *reinterpret_cast<const bf16x8*>(BfT + bo_);
      bI[ks] = *reinterpret_cast<const bf16x8*>(BihT + bo_);
      bU[ks] = *reinterpret_cast<const bf16x8*>(BuhT + bo_);
      bO[ks] = *reinterpret_cast<const bf16x8*>(BohT + bo_);
    }
#pragma unroll
    for (int i = 0; i < NCI; i++) {
      floatx4 aF = {0.f,0.f,0.f,0.f}, aI = {0.f,0.f,0.f,0.f};
      floatx4 aU = {0.f,0.f,0.f,0.f}, aO = {0.f,0.f,0.f,0.f};
#pragma unroll
      for (int ks = 0; ks < 4; ks++) {
        bf16x8 a = *reinterpret_cast<const bf16x8*>(&ldsA[swz128(i * 16 + l16, ks * 4 + quad)]);
        aF = __builtin_amdgcn_mfma_f32_16x16x32_bf16(a, bF[ks], aF, 0, 0, 0);
        aI = __builtin_amdgcn_mfma_f32_16x16x32_bf16(a, bI[ks], aI, 0, 0, 0);
        aU = __builtin_amdgcn_mfma_f32_16x16x32_bf16(a, bU[ks], aU, 0, 0, 0);
        aO = __builtin_amdgcn_mfma_f32_16x16x32_bf16(a, bO[ks], aO, 0, 0, 0);
      }
      const int rbase = i * 16 + quad * 4;
#pragma unroll
      for (int t = 0; t < RTI; t++) {
        const int p = (rbase >> LR) + t;
        ushort4 g4 = *reinterpret_cast<const ushort4*>(Ep + (size_t)sidP[p] * 512 + col * 4);
        const float epf = bf2f(g4.w);
        float fsum = 0.f, isum = 0.f, usum = 0.f, osum = 0.f;
#pragma unroll
        for (int r2 = t * RT; r2 < t * RT + RT; r2++) {
          const int row = rbase + r2;
          const float cch = LEAF ? bf2f(ldsC[swze(row, col)])
                                 : bf2f(c_prev[(cb + row) * 128 + col]);
          fsum += sigmoidf_(aF[r2] + epf) * cch;
          isum += aI[r2]; usum += aU[r2]; osum += aO[r2];
        }
        const float c = sigmoidf_(isum + bf2f(g4.x)) * tanhf_(usum + bf2f(g4.y)) + fsum;
        const float h = sigmoidf_(osum + bf2f(g4.z)) * tanhf_(c);
        c_out[(p0 + p) * 128 + col] = f2bf(c);
        h_out[(p0 + p) * 128 + col] = f2bf(h);
      }
    }
  }
}

// ---------- weight/bias prep ----------
__global__ void build_wallT(const float* __restrict__ Wix, const float* __restrict__ Wux,
                            const float* __restrict__ Wox, const float* __restrict__ Wfx,
                            u16* __restrict__ WT)
{
  int idx = blockIdx.x * 256 + threadIdx.x;   // 512*128
  int n = idx >> 7, k = idx & 127;
  int g = n >> 7, j = n & 127;
  const float* W = (g == 0) ? Wix : (g == 1) ? Wux : (g == 2) ? Wox : Wfx;
  WT[idx] = f2bf(W[k * 128 + j]);
}

__global__ void build_bsum(const float* __restrict__ b_ix, const float* __restrict__ b_ih,
                           const float* __restrict__ b_ux, const float* __restrict__ b_uh,
                           const float* __restrict__ b_ox, const float* __restrict__ b_oh,
                           const float* __restrict__ b_fx, const float* __restrict__ b_fh,
                           float* __restrict__ bsum)
{
  int n = blockIdx.x * 256 + threadIdx.x;   // 512
  int g = n >> 7, j = n & 127;
  float v = (g == 0) ? b_ix[j] + b_ih[j] : (g == 1) ? b_ux[j] + b_uh[j]
          : (g == 2) ? b_ox[j] + b_oh[j] : b_fx[j] + b_fh[j];
  bsum[n] = v;
}

__global__ void build_bt128(const float* __restrict__ W, u16* __restrict__ BT) {
  int idx = blockIdx.x * 256 + threadIdx.x;   // 128*128
  int n = idx >> 7, k = idx & 127;
  BT[idx] = f2bf(W[k * 128 + n]);
}

// ---------- output projection (4096 x 4, tiny) ----------
__global__ void out_proj(const u16* __restrict__ h_root, const float* __restrict__ W_out,
                         const float* __restrict__ b_out, float* __restrict__ out)
{
  int idx = blockIdx.x * 256 + threadIdx.x;   // 4096*4
  int n = idx >> 2, cls = idx & 3;
  float s = b_out[cls];
  for (int k = 0; k < 128; k++)
    s += bf2f(h_root[(long)n * 128 + k]) * W_out[k * 4 + cls];
  out[idx] = s;
}

extern "C" void kernel_launch(void* const* d_in, const int* in_sizes, int n_in,
                              void* d_out, int out_size, void* d_ws, size_t ws_size,
                              hipStream_t stream)
{
  const int*   sen  = (const int*)d_in[0];
  const float* emb  = (const float*)d_in[1];
  const float* W_ix = (const float*)d_in[2];  const float* b_ix = (const float*)d_in[3];
  const float* W_ih = (const float*)d_in[4];  const float* b_ih = (const float*)d_in[5];
  const float* W_fx = (const float*)d_in[6];  const float* b_fx = (const float*)d_in[7];
  const float* W_fh = (const float*)d_in[8];  const float* b_fh = (const float*)d_in[9];
  const float* W_ox = (const float*)d_in[10]; const float* b_ox = (const float*)d_in[11];
  const float* W_oh = (const float*)d_in[12]; const float* b_oh = (const float*)d_in[13];
  const float* W_ux = (const float*)d_in[14]; const float* b_ux = (const float*)d_in[15];
  const float* W_uh = (const float*)d_in[16]; const float* b_uh = (const float*)d_in[17];
  const float* W_out= (const float*)d_in[18]; const float* b_out= (const float*)d_in[19];
  float* out = (float*)d_out;

  // ---- workspace ----
  // Permanent: hA, cA (L4/L2/L0 outputs), Ep, weights.
  // Scratch S (67.1 MB): during leaf prep + L4 holds Cl (12.8 MB) + Gh (51.2 MB);
  // from L3 onward it is hB/cB (L3/L1 outputs). L3 launches after L4 has consumed
  // Cl/Gh, so the overwrite is safe (stream-ordered).
  const size_t AH  = (size_t)262144 * 128;          // u16 elems
  const size_t BH  = (size_t)131072 * 128;
  const size_t EPB = (size_t)50000 * 512 * 2;       // Ep / Gh bytes
  const size_t CLB = (size_t)50000 * 128 * 2;       // Cl bytes
  const size_t SCR = 2 * BH * 2;                    // 67.1 MB >= CLB + EPB (64 MB)
  const size_t need = 2 * AH * 2 + SCR + EPB
                    + (size_t)512 * 128 * 2 + 4 * (size_t)128 * 128 * 2 + 512 * 4 + 4096;
  fprintf(stderr, "[tree_lstm] ws_size=%zu need=%zu\n", ws_size, need);
  if (ws_size < need) {
    fprintf(stderr, "[tree_lstm] INSUFFICIENT WORKSPACE — skipping launch\n");
    return;
  }
  char* ws = (char*)d_ws;
  size_t off = 0;
  auto take = [&](size_t bytes) { char* p = ws + off; off += (bytes + 255) & ~(size_t)255; return p; };
  u16* hA = (u16*)take(AH * 2);
  u16* cA = (u16*)take(AH * 2);
  char* S  = take(SCR);
  u16* Ep = (u16*)take(EPB);
  u16* WallT = (u16*)take((size_t)512 * 128 * 2);
  u16* BihT = (u16*)take((size_t)128 * 128 * 2);
  u16* BuhT = (u16*)take((size_t)128 * 128 * 2);
  u16* BohT = (u16*)take((size_t)128 * 128 * 2);
  u16* BfhT = (u16*)take((size_t)128 * 128 * 2);
  float* bsum = (float*)take(512 * 4);

  // scratch views
  u16* Cl = (u16*)S;                 // leaf c per vocab word
  u16* Gh = (u16*)(S + CLB);         // h-side pre-acts per vocab word (CLB is 256-aligned)
  u16* hB = (u16*)S;                 // L3/L1 h (after L4)
  u16* cB = (u16*)(S + BH * 2);      // L3/L1 c (after L4)

  // ---- prep ----
  build_wallT<<<256, 256, 0, stream>>>(W_ix, W_ux, W_ox, W_fx, WallT);
  build_bsum<<<2, 256, 0, stream>>>(b_ix, b_ih, b_ux, b_uh, b_ox, b_oh, b_fx, b_fh, bsum);
  build_bt128<<<64, 256, 0, stream>>>(W_ih, BihT);
  build_bt128<<<64, 256, 0, stream>>>(W_uh, BuhT);
  build_bt128<<<64, 256, 0, stream>>>(W_oh, BohT);
  build_bt128<<<64, 256, 0, stream>>>(W_fh, BfhT);
  proj_e<<<391, 256, 0, stream>>>(emb, WallT, bsum, Ep);
  proj_hc<<<391, 256, 0, stream>>>(Ep, BihT, BuhT, BohT, BfhT, Cl, Gh);

  const long LOFF[6] = {0, 4096, 20480, 86016, 217088, 479232};

  // L4 (parents 262144, ratio 1): elementwise gather via vocab-space Ep/Gh/Cl tables
  l4_leaf<<<65536, 256, 0, stream>>>(sen, Ep, Gh, Cl, cA, hA, LOFF[4], LOFF[5]);
  // L3 (131072, ratio 2) A -> B
  k_level<1, false><<<2048, 256, 0, stream>>>(sen, Ep, hA, cA,
      BfhT, BihT, BuhT, BohT, cB, hB, LOFF[3], 0);
  // L2 (65536, ratio 2) B -> A
  k_level<1, false><<<1024, 256, 0, stream>>>(sen, Ep, hB, cB,
      BfhT, BihT, BuhT, BohT, cA, hA, LOFF[2], 0);
  // L1 (16384, ratio 4) A -> B
  k_level<2, false><<<512, 256, 0, stream>>>(sen, Ep, hA, cA,
      BfhT, BihT, BuhT, BohT, cB, hB, LOFF[1], 0);
  // L0 (4096, ratio 4) B -> A
  k_level<2, false><<<128, 256, 0, stream>>>(sen, Ep, hB, cB,
      BfhT, BihT, BuhT, BohT, cA, hA, LOFF[0], 0);

  out_proj<<<64, 256, 0, stream>>>(hA, W_out, b_out, out);
}

// Round 4
// 520.285 us; speedup vs baseline: 1.1791x; 1.0407x over previous
//
#include <hip/hip_runtime.h>
#include <hip/hip_bf16.h>
#include <cstdio>

typedef unsigned short u16;
typedef __bf16 bf16x8 __attribute__((ext_vector_type(8)));
typedef float  floatx4 __attribute__((ext_vector_type(4)));

// ---------- scalar helpers ----------
__device__ __forceinline__ float bf2f(u16 u) {
  union { unsigned int i; float f; } v; v.i = ((unsigned int)u) << 16; return v.f;
}
__device__ __forceinline__ u16 f2bf(float f) {
  union { float f; unsigned int i; } v; v.f = f;
  unsigned int x = v.i;
  return (u16)((x + 0x7fffu + ((x >> 16) & 1u)) >> 16);   // RNE
}
__device__ __forceinline__ unsigned int f2bf_pk(float a, float b) {   // [lo=a, hi=b]
  __hip_bfloat162 h = __float22bfloat162_rn(make_float2(a, b));
  union { __hip_bfloat162 h; unsigned int u; } v; v.h = h; return v.u;
}
// fast gates: v_rcp (~1 ulp) + native exp — no IEEE div
__device__ __forceinline__ float sigmoidf_(float x) {
  return __builtin_amdgcn_rcpf(1.f + __expf(-x));
}
__device__ __forceinline__ float tanhf_(float x) {
  return fmaf(-2.f, __builtin_amdgcn_rcpf(1.f + __expf(2.f * x)), 1.f);
}

// LDS swizzle, 128-elem rows, 16B chunks: chunk' = chunk ^ (row&15)
__device__ __forceinline__ int swz128(int row, int c16) {
  return row * 128 + ((c16 ^ (row & 15)) << 3);
}
// element-level access into swizzled rows
__device__ __forceinline__ int swze(int row, int col) {
  return row * 128 + (((((col >> 3)) ^ (row & 15)) << 3) | (col & 7));
}

// ============ proj_e: Ep[v][col][4] = {i,u,o,f} pre-acts + biases (gate-interleaved) ============
__global__ __launch_bounds__(256, 2) void proj_e(
    const float* __restrict__ emb, const u16* __restrict__ WT,
    const float* __restrict__ bsum, u16* __restrict__ Ep)
{
  __shared__ __align__(16) u16 ldsA[128 * 128];
  const int tid = threadIdx.x;
  const long m0 = (long)blockIdx.x * 128;
  {
    const int r = tid >> 1, half = tid & 1;
    long row = m0 + r; if (row > 49999) row = 49999;
    const float* src = emb + row * 128 + half * 64;
#pragma unroll
    for (int i = 0; i < 8; i++) {
      float4 v0 = *reinterpret_cast<const float4*>(src + i * 8);
      float4 v1 = *reinterpret_cast<const float4*>(src + i * 8 + 4);
      unsigned int ov[4] = { f2bf_pk(v0.x, v0.y), f2bf_pk(v0.z, v0.w),
                             f2bf_pk(v1.x, v1.y), f2bf_pk(v1.z, v1.w) };
      *reinterpret_cast<uint4*>(&ldsA[swz128(r, half * 8 + i)]) =
          *reinterpret_cast<const uint4*>(ov);
    }
  }
  __syncthreads();
  const int lane = tid & 63, w = tid >> 6, l16 = lane & 15, quad = lane >> 4;
#pragma unroll
  for (int half = 0; half < 2; half++) {
    const int col = w * 32 + half * 16 + l16;
    bf16x8 bI[4], bU[4], bO[4], bF[4];
#pragma unroll
    for (int ks = 0; ks < 4; ks++) {
      const size_t o_ = ks * 32 + quad * 8;
      bI[ks] = *reinterpret_cast<const bf16x8*>(WT + (size_t)(0   + col) * 128 + o_);
      bU[ks] = *reinterpret_cast<const bf16x8*>(WT + (size_t)(128 + col) * 128 + o_);
      bO[ks] = *reinterpret_cast<const bf16x8*>(WT + (size_t)(256 + col) * 128 + o_);
      bF[ks] = *reinterpret_cast<const bf16x8*>(WT + (size_t)(384 + col) * 128 + o_);
    }
    const float bi = bsum[col], bu = bsum[128 + col], bo = bsum[256 + col], bf = bsum[384 + col];
#pragma unroll
    for (int i = 0; i < 8; i++) {
      floatx4 aI = {0.f,0.f,0.f,0.f}, aU = {0.f,0.f,0.f,0.f};
      floatx4 aO = {0.f,0.f,0.f,0.f}, aF = {0.f,0.f,0.f,0.f};
#pragma unroll
      for (int ks = 0; ks < 4; ks++) {
        bf16x8 a = *reinterpret_cast<const bf16x8*>(&ldsA[swz128(i * 16 + l16, ks * 4 + quad)]);
        aI = __builtin_amdgcn_mfma_f32_16x16x32_bf16(a, bI[ks], aI, 0, 0, 0);
        aU = __builtin_amdgcn_mfma_f32_16x16x32_bf16(a, bU[ks], aU, 0, 0, 0);
        aO = __builtin_amdgcn_mfma_f32_16x16x32_bf16(a, bO[ks], aO, 0, 0, 0);
        aF = __builtin_amdgcn_mfma_f32_16x16x32_bf16(a, bF[ks], aF, 0, 0, 0);
      }
#pragma unroll
      for (int r2 = 0; r2 < 4; r2++) {
        const long row = m0 + i * 16 + quad * 4 + r2;
        if (row < 50000) {
          u16 ov[4] = { f2bf(aI[r2] + bi), f2bf(aU[r2] + bu),
                        f2bf(aO[r2] + bo), f2bf(aF[r2] + bf) };
          *reinterpret_cast<ushort4*>(Ep + row * 512 + col * 4) =
              *reinterpret_cast<const ushort4*>(ov);
        }
      }
    }
  }
}

// ============ proj_hc: fused leaf activations + h-side projection ============
// Staging: Ep[v] -> leaf h (LDS, swizzled) and leaf c -> Cl[v] (global).
// MFMA:    Gh[v][col][4] = {i,u,o,f} h-side pre-acts = Hleaf[v] @ W_*h (no bias).
__global__ __launch_bounds__(256, 2) void proj_hc(
    const u16* __restrict__ Ep,
    const u16* __restrict__ BihT, const u16* __restrict__ BuhT,
    const u16* __restrict__ BohT, const u16* __restrict__ BfT,
    u16* __restrict__ Cl, u16* __restrict__ Gh)
{
  __shared__ __align__(16) u16 ldsA[128 * 128];
  const int tid = threadIdx.x;
  const long m0 = (long)blockIdx.x * 128;
  {
    const int r = tid >> 1, half = tid & 1;
    long row = m0 + r;
    const bool ok = (row < 50000); if (!ok) row = 49999;
    const u16* src = Ep + row * 512 + half * 256;
#pragma unroll
    for (int i = 0; i < 8; i++) {
      uint4 v[4];
#pragma unroll
      for (int k = 0; k < 4; k++)
        v[k] = *reinterpret_cast<const uint4*>(src + i * 32 + k * 8);
      unsigned int hp[4], cp[4];
#pragma unroll
      for (int k = 0; k < 4; k++) {      // each uint4 = 2 cols x {i,u,o,f}
        const u16* p = reinterpret_cast<const u16*>(&v[k]);
        float c0 = sigmoidf_(bf2f(p[0])) * tanhf_(bf2f(p[1]));
        float c1 = sigmoidf_(bf2f(p[4])) * tanhf_(bf2f(p[5]));
        float h0 = sigmoidf_(bf2f(p[2])) * tanhf_(c0);
        float h1 = sigmoidf_(bf2f(p[6])) * tanhf_(c1);
        cp[k] = f2bf_pk(c0, c1);
        hp[k] = f2bf_pk(h0, h1);
      }
      *reinterpret_cast<uint4*>(&ldsA[swz128(r, half * 8 + i)]) =
          *reinterpret_cast<const uint4*>(hp);
      if (ok)
        *reinterpret_cast<uint4*>(Cl + row * 128 + half * 64 + i * 8) =
            *reinterpret_cast<const uint4*>(cp);
    }
  }
  __syncthreads();
  const int lane = tid & 63, w = tid >> 6, l16 = lane & 15, quad = lane >> 4;
#pragma unroll
  for (int half = 0; half < 2; half++) {
    const int col = w * 32 + half * 16 + l16;
    bf16x8 bI[4], bU[4], bO[4], bF[4];
#pragma unroll
    for (int ks = 0; ks < 4; ks++) {
      const size_t o_ = (size_t)col * 128 + ks * 32 + quad * 8;
      bI[ks] = *reinterpret_cast<const bf16x8*>(BihT + o_);
      bU[ks] = *reinterpret_cast<const bf16x8*>(BuhT + o_);
      bO[ks] = *reinterpret_cast<const bf16x8*>(BohT + o_);
      bF[ks] = *reinterpret_cast<const bf16x8*>(BfT  + o_);
    }
#pragma unroll
    for (int i = 0; i < 8; i++) {
      floatx4 aI = {0.f,0.f,0.f,0.f}, aU = {0.f,0.f,0.f,0.f};
      floatx4 aO = {0.f,0.f,0.f,0.f}, aF = {0.f,0.f,0.f,0.f};
#pragma unroll
      for (int ks = 0; ks < 4; ks++) {
        bf16x8 a = *reinterpret_cast<const bf16x8*>(&ldsA[swz128(i * 16 + l16, ks * 4 + quad)]);
        aI = __builtin_amdgcn_mfma_f32_16x16x32_bf16(a, bI[ks], aI, 0, 0, 0);
        aU = __builtin_amdgcn_mfma_f32_16x16x32_bf16(a, bU[ks], aU, 0, 0, 0);
        aO = __builtin_amdgcn_mfma_f32_16x16x32_bf16(a, bO[ks], aO, 0, 0, 0);
        aF = __builtin_amdgcn_mfma_f32_16x16x32_bf16(a, bF[ks], aF, 0, 0, 0);
      }
#pragma unroll
      for (int r2 = 0; r2 < 4; r2++) {
        const long row = m0 + i * 16 + quad * 4 + r2;
        if (row < 50000) {
          u16 ov[4] = { f2bf(aI[r2]), f2bf(aU[r2]), f2bf(aO[r2]), f2bf(aF[r2]) };
          *reinterpret_cast<ushort4*>(Gh + row * 512 + col * 4) =
              *reinterpret_cast<const ushort4*>(ov);
        }
      }
    }
  }
}

// ============ k_l3fused: L4 computed inline during staging, then L3 tree-LSTM step ============
// Staging per child row r (an L4 node): vp = its vocab id, vc = its leaf child's id.
// gates = act(Ep[vp] + Gh[vc]); c4 = i*u + f*Cl[vc]; h4 = o*tanh(c4)  [identical to old l4_leaf]
// h4 -> ldsA (swz, bf16), c4 -> ldsC (swz, bf16). Then the standard LR=1 LEAF epilogue.
// Saves the 134 MB h/c HBM write + 134 MB re-read of the separate-l4_leaf scheme.
__global__ __launch_bounds__(256, 2) void k_l3fused(
    const int* __restrict__ sen, const u16* __restrict__ Ep,
    const u16* __restrict__ Gh, const u16* __restrict__ Cl,
    const u16* __restrict__ BfT, const u16* __restrict__ BihT,
    const u16* __restrict__ BuhT, const u16* __restrict__ BohT,
    u16* __restrict__ c_out, u16* __restrict__ h_out,
    long o0, long o1, long o2)
{
  constexpr int PM = 64, CM = 128, NCI = 8, RT = 2;
  __shared__ __align__(16) u16 ldsA[CM * 128];   // L4 h (swz)
  __shared__ __align__(16) u16 ldsC[CM * 128];   // L4 c (swz)
  __shared__ int sidP[PM];

  const int tid = threadIdx.x;
  const long p0 = (long)blockIdx.x * PM;
  const long cb = (long)blockIdx.x * CM;

  // ---- stage: compute L4 children in place ----
  {
    const int r = tid >> 1, q = tid & 1;          // 2 threads per child row, 64 cols each
    const size_t vp = (size_t)sen[o1 + cb + r];   // L4 node vocab id
    const size_t vc = (size_t)sen[o2 + cb + r];   // its leaf child's vocab id
    const u16* ep = Ep + vp * 512 + q * 256;
    const u16* gh = Gh + vc * 512 + q * 256;
    const u16* cl = Cl + vc * 128 + q * 64;
#pragma unroll
    for (int ii = 0; ii < 8; ii++) {              // 8 cols per iteration
      uint4 ev[4], gv[4];
#pragma unroll
      for (int k = 0; k < 4; k++) {
        ev[k] = *reinterpret_cast<const uint4*>(ep + ii * 32 + k * 8);
        gv[k] = *reinterpret_cast<const uint4*>(gh + ii * 32 + k * 8);
      }
      uint4 cvv = *reinterpret_cast<const uint4*>(cl + ii * 8);
      const u16* cp = reinterpret_cast<const u16*>(&cvv);
      unsigned int hp[4], cpk[4];
#pragma unroll
      for (int k = 0; k < 4; k++) {               // 2 cols per k
        const u16* e = reinterpret_cast<const u16*>(&ev[k]);
        const u16* g = reinterpret_cast<const u16*>(&gv[k]);
        const float i0 = sigmoidf_(bf2f(e[0]) + bf2f(g[0]));
        const float u0 = tanhf_   (bf2f(e[1]) + bf2f(g[1]));
        const float og0= sigmoidf_(bf2f(e[2]) + bf2f(g[2]));
        const float f0 = sigmoidf_(bf2f(e[3]) + bf2f(g[3]));
        const float i1 = sigmoidf_(bf2f(e[4]) + bf2f(g[4]));
        const float u1 = tanhf_   (bf2f(e[5]) + bf2f(g[5]));
        const float og1= sigmoidf_(bf2f(e[6]) + bf2f(g[6]));
        const float f1 = sigmoidf_(bf2f(e[7]) + bf2f(g[7]));
        const float c0 = fmaf(i0, u0, f0 * bf2f(cp[k * 2]));
        const float c1 = fmaf(i1, u1, f1 * bf2f(cp[k * 2 + 1]));
        const float h0 = og0 * tanhf_(c0);
        const float h1 = og1 * tanhf_(c1);
        hp[k]  = f2bf_pk(h0, h1);
        cpk[k] = f2bf_pk(c0, c1);
      }
      *reinterpret_cast<uint4*>(&ldsA[swz128(r, q * 8 + ii)]) =
          *reinterpret_cast<const uint4*>(hp);
      *reinterpret_cast<uint4*>(&ldsC[swz128(r, q * 8 + ii)]) =
          *reinterpret_cast<const uint4*>(cpk);
    }
    if (tid < PM) sidP[tid] = sen[o0 + p0 + tid];
  }
  __syncthreads();

  const int lane = tid & 63, w = tid >> 6, l16 = lane & 15, quad = lane >> 4;

#pragma unroll
  for (int gl = 0; gl < 2; gl++) {
    const int col = w * 32 + gl * 16 + l16;
    bf16x8 bF[4], bI[4], bU[4], bO[4];
#pragma unroll
    for (int ks = 0; ks < 4; ks++) {
      const size_t bo_ = (size_t)col * 128 + ks * 32 + quad * 8;
      bF[ks] = *reinterpret_cast<const bf16x8*>(BfT + bo_);
      bI[ks] = *reinterpret_cast<const bf16x8*>(BihT + bo_);
      bU[ks] = *reinterpret_cast<const bf16x8*>(BuhT + bo_);
      bO[ks] = *reinterpret_cast<const bf16x8*>(BohT + bo_);
    }
#pragma unroll
    for (int i = 0; i < NCI; i++) {
      floatx4 aF = {0.f,0.f,0.f,0.f}, aI = {0.f,0.f,0.f,0.f};
      floatx4 aU = {0.f,0.f,0.f,0.f}, aO = {0.f,0.f,0.f,0.f};
#pragma unroll
      for (int ks = 0; ks < 4; ks++) {
        bf16x8 a = *reinterpret_cast<const bf16x8*>(&ldsA[swz128(i * 16 + l16, ks * 4 + quad)]);
        aF = __builtin_amdgcn_mfma_f32_16x16x32_bf16(a, bF[ks], aF, 0, 0, 0);
        aI = __builtin_amdgcn_mfma_f32_16x16x32_bf16(a, bI[ks], aI, 0, 0, 0);
        aU = __builtin_amdgcn_mfma_f32_16x16x32_bf16(a, bU[ks], aU, 0, 0, 0);
        aO = __builtin_amdgcn_mfma_f32_16x16x32_bf16(a, bO[ks], aO, 0, 0, 0);
      }
      const int rbase = i * 16 + quad * 4;
#pragma unroll
      for (int t = 0; t < 2; t++) {
        const int p = (rbase >> 1) + t;
        ushort4 g4 = *reinterpret_cast<const ushort4*>(Ep + (size_t)sidP[p] * 512 + col * 4);
        const float epf = bf2f(g4.w);
        float fsum = 0.f, isum = 0.f, usum = 0.f, osum = 0.f;
#pragma unroll
        for (int r2 = t * RT; r2 < t * RT + RT; r2++) {
          const int row = rbase + r2;
          const float cch = bf2f(ldsC[swze(row, col)]);
          fsum += sigmoidf_(aF[r2] + epf) * cch;
          isum += aI[r2]; usum += aU[r2]; osum += aO[r2];
        }
        const float c = sigmoidf_(isum + bf2f(g4.x)) * tanhf_(usum + bf2f(g4.y)) + fsum;
        const float h = sigmoidf_(osum + bf2f(g4.z)) * tanhf_(c);
        c_out[(p0 + p) * 128 + col] = f2bf(c);
        h_out[(p0 + p) * 128 + col] = f2bf(h);
      }
    }
  }
}

// ============ k_level: per-i-tile fused f/i/u/o (inner levels, computed children) ============
template<int LR>
__global__ __launch_bounds__(256, 2) void k_level(
    const int* __restrict__ sen, const u16* __restrict__ Ep,
    const u16* __restrict__ h_prev, const u16* __restrict__ c_prev,
    const u16* __restrict__ BfT, const u16* __restrict__ BihT,
    const u16* __restrict__ BuhT, const u16* __restrict__ BohT,
    u16* __restrict__ c_out, u16* __restrict__ h_out,
    long o0)
{
  constexpr int PM  = (LR == 2) ? 32 : 64;
  constexpr int CM  = PM << LR;
  constexpr int NCI = CM / 16;
  constexpr int RT  = 1 << LR;
  constexpr int RTI = 4 >> LR;         // parents per 4-row quad block
  constexpr int TPR = 256 / CM;        // staging threads per child row
  __shared__ __align__(16) u16 ldsA[CM * 128];   // child h (swz)
  __shared__ int sidP[PM];

  const int tid = threadIdx.x;
  const long p0 = (long)blockIdx.x * PM;
  const long cb = (long)blockIdx.x * CM;

  // ---- stage children ----
  {
    const int r = tid / TPR, q = tid % TPR;
    constexpr int CH = 16 / TPR;
    const u16* src = h_prev + (cb + r) * 128;
#pragma unroll
    for (int ii = 0; ii < CH; ii++) {
      const int c16 = q * CH + ii;
      *reinterpret_cast<uint4*>(&ldsA[swz128(r, c16)]) =
          *reinterpret_cast<const uint4*>(src + c16 * 8);
    }
    if (tid < PM) sidP[tid] = sen[o0 + p0 + tid];
  }
  __syncthreads();

  const int lane = tid & 63, w = tid >> 6, l16 = lane & 15, quad = lane >> 4;

#pragma unroll
  for (int gl = 0; gl < 2; gl++) {
    const int col = w * 32 + gl * 16 + l16;
    bf16x8 bF[4], bI[4], bU[4], bO[4];
#pragma unroll
    for (int ks = 0; ks < 4; ks++) {
      const size_t bo_ = (size_t)col * 128 + ks * 32 + quad * 8;
      bF[ks] = *reinterpret_cast<const bf16x8*>(BfT + bo_);
      bI[ks] = *reinterpret_cast<const bf16x8*>(BihT + bo_);
      bU[ks] = *reinterpret_cast<const bf16x8*>(BuhT + bo_);
      bO[ks] = *reinterpret_cast<const bf16x8*>(BohT + bo_);
    }
#pragma unroll
    for (int i = 0; i < NCI; i++) {
      floatx4 aF = {0.f,0.f,0.f,0.f}, aI = {0.f,0.f,0.f,0.f};
      floatx4 aU = {0.f,0.f,0.f,0.f}, aO = {0.f,0.f,0.f,0.f};
#pragma unroll
      for (int ks = 0; ks < 4; ks++) {
        bf16x8 a = *reinterpret_cast<const bf16x8*>(&ldsA[swz128(i * 16 + l16, ks * 4 + quad)]);
        aF = __builtin_amdgcn_mfma_f32_16x16x32_bf16(a, bF[ks], aF, 0, 0, 0);
        aI = __builtin_amdgcn_mfma_f32_16x16x32_bf16(a, bI[ks], aI, 0, 0, 0);
        aU = __builtin_amdgcn_mfma_f32_16x16x32_bf16(a, bU[ks], aU, 0, 0, 0);
        aO = __builtin_amdgcn_mfma_f32_16x16x32_bf16(a, bO[ks], aO, 0, 0, 0);
      }
      const int rbase = i * 16 + quad * 4;
#pragma unroll
      for (int t = 0; t < RTI; t++) {
        const int p = (rbase >> LR) + t;
        ushort4 g4 = *reinterpret_cast<const ushort4*>(Ep + (size_t)sidP[p] * 512 + col * 4);
        const float epf = bf2f(g4.w);
        float fsum = 0.f, isum = 0.f, usum = 0.f, osum = 0.f;
#pragma unroll
        for (int r2 = t * RT; r2 < t * RT + RT; r2++) {
          const int row = rbase + r2;
          const float cch = bf2f(c_prev[(cb + row) * 128 + col]);
          fsum += sigmoidf_(aF[r2] + epf) * cch;
          isum += aI[r2]; usum += aU[r2]; osum += aO[r2];
        }
        const float c = sigmoidf_(isum + bf2f(g4.x)) * tanhf_(usum + bf2f(g4.y)) + fsum;
        const float h = sigmoidf_(osum + bf2f(g4.z)) * tanhf_(c);
        c_out[(p0 + p) * 128 + col] = f2bf(c);
        h_out[(p0 + p) * 128 + col] = f2bf(h);
      }
    }
  }
}

// ---------- weight/bias prep ----------
__global__ void build_wallT(const float* __restrict__ Wix, const float* __restrict__ Wux,
                            const float* __restrict__ Wox, const float* __restrict__ Wfx,
                            u16* __restrict__ WT)
{
  int idx = blockIdx.x * 256 + threadIdx.x;   // 512*128
  int n = idx >> 7, k = idx & 127;
  int g = n >> 7, j = n & 127;
  const float* W = (g == 0) ? Wix : (g == 1) ? Wux : (g == 2) ? Wox : Wfx;
  WT[idx] = f2bf(W[k * 128 + j]);
}

__global__ void build_bsum(const float* __restrict__ b_ix, const float* __restrict__ b_ih,
                           const float* __restrict__ b_ux, const float* __restrict__ b_uh,
                           const float* __restrict__ b_ox, const float* __restrict__ b_oh,
                           const float* __restrict__ b_fx, const float* __restrict__ b_fh,
                           float* __restrict__ bsum)
{
  int n = blockIdx.x * 256 + threadIdx.x;   // 512
  int g = n >> 7, j = n & 127;
  float v = (g == 0) ? b_ix[j] + b_ih[j] : (g == 1) ? b_ux[j] + b_uh[j]
          : (g == 2) ? b_ox[j] + b_oh[j] : b_fx[j] + b_fh[j];
  bsum[n] = v;
}

__global__ void build_bt128(const float* __restrict__ W, u16* __restrict__ BT) {
  int idx = blockIdx.x * 256 + threadIdx.x;   // 128*128
  int n = idx >> 7, k = idx & 127;
  BT[idx] = f2bf(W[k * 128 + n]);
}

// ---------- output projection (4096 x 4, tiny) ----------
__global__ void out_proj(const u16* __restrict__ h_root, const float* __restrict__ W_out,
                         const float* __restrict__ b_out, float* __restrict__ out)
{
  int idx = blockIdx.x * 256 + threadIdx.x;   // 4096*4
  int n = idx >> 2, cls = idx & 3;
  float s = b_out[cls];
  for (int k = 0; k < 128; k++)
    s += bf2f(h_root[(long)n * 128 + k]) * W_out[k * 4 + cls];
  out[idx] = s;
}

extern "C" void kernel_launch(void* const* d_in, const int* in_sizes, int n_in,
                              void* d_out, int out_size, void* d_ws, size_t ws_size,
                              hipStream_t stream)
{
  const int*   sen  = (const int*)d_in[0];
  const float* emb  = (const float*)d_in[1];
  const float* W_ix = (const float*)d_in[2];  const float* b_ix = (const float*)d_in[3];
  const float* W_ih = (const float*)d_in[4];  const float* b_ih = (const float*)d_in[5];
  const float* W_fx = (const float*)d_in[6];  const float* b_fx = (const float*)d_in[7];
  const float* W_fh = (const float*)d_in[8];  const float* b_fh = (const float*)d_in[9];
  const float* W_ox = (const float*)d_in[10]; const float* b_ox = (const float*)d_in[11];
  const float* W_oh = (const float*)d_in[12]; const float* b_oh = (const float*)d_in[13];
  const float* W_ux = (const float*)d_in[14]; const float* b_ux = (const float*)d_in[15];
  const float* W_uh = (const float*)d_in[16]; const float* b_uh = (const float*)d_in[17];
  const float* W_out= (const float*)d_in[18]; const float* b_out= (const float*)d_in[19];
  float* out = (float*)d_out;

  // ---- workspace: every buffer distinct (no aliasing; L4 h/c never materialized) ----
  const size_t EPB = (size_t)50000 * 512 * 2;       // Ep / Gh bytes (51.2 MB each)
  const size_t CLB = (size_t)50000 * 128 * 2;       // Cl bytes (12.8 MB)
  const size_t H3  = (size_t)131072 * 128 * 2;      // 33.55 MB each
  const size_t H2  = (size_t)65536  * 128 * 2;
  const size_t H1  = (size_t)16384  * 128 * 2;
  const size_t H0  = (size_t)4096   * 128 * 2;
  const size_t need = 2 * EPB + CLB + 2 * (H3 + H2 + H1 + H0)
                    + (size_t)512 * 128 * 2 + 4 * (size_t)128 * 128 * 2 + 512 * 4 + 8192;
  fprintf(stderr, "[tree_lstm] ws_size=%zu need=%zu\n", ws_size, need);
  if (ws_size < need) {
    fprintf(stderr, "[tree_lstm] INSUFFICIENT WORKSPACE — skipping launch\n");
    return;
  }
  char* ws = (char*)d_ws;
  size_t off = 0;
  auto take = [&](size_t bytes) { char* p = ws + off; off += (bytes + 255) & ~(size_t)255; return p; };
  u16* Ep = (u16*)take(EPB);
  u16* Gh = (u16*)take(EPB);
  u16* Cl = (u16*)take(CLB);
  u16* h3 = (u16*)take(H3);  u16* c3 = (u16*)take(H3);
  u16* h2 = (u16*)take(H2);  u16* c2 = (u16*)take(H2);
  u16* h1 = (u16*)take(H1);  u16* c1 = (u16*)take(H1);
  u16* h0 = (u16*)take(H0);  u16* c0 = (u16*)take(H0);
  u16* WallT = (u16*)take((size_t)512 * 128 * 2);
  u16* BihT = (u16*)take((size_t)128 * 128 * 2);
  u16* BuhT = (u16*)take((size_t)128 * 128 * 2);
  u16* BohT = (u16*)take((size_t)128 * 128 * 2);
  u16* BfhT = (u16*)take((size_t)128 * 128 * 2);
  float* bsum = (float*)take(512 * 4);

  // ---- prep ----
  build_wallT<<<256, 256, 0, stream>>>(W_ix, W_ux, W_ox, W_fx, WallT);
  build_bsum<<<2, 256, 0, stream>>>(b_ix, b_ih, b_ux, b_uh, b_ox, b_oh, b_fx, b_fh, bsum);
  build_bt128<<<64, 256, 0, stream>>>(W_ih, BihT);
  build_bt128<<<64, 256, 0, stream>>>(W_uh, BuhT);
  build_bt128<<<64, 256, 0, stream>>>(W_oh, BohT);
  build_bt128<<<64, 256, 0, stream>>>(W_fh, BfhT);
  proj_e<<<391, 256, 0, stream>>>(emb, WallT, bsum, Ep);
  proj_hc<<<391, 256, 0, stream>>>(Ep, BihT, BuhT, BohT, BfhT, Cl, Gh);

  const long LOFF[6] = {0, 4096, 20480, 86016, 217088, 479232};

  // L3 (131072 parents) with L4 (ratio-1 leaf level) computed inline in staging
  k_l3fused<<<2048, 256, 0, stream>>>(sen, Ep, Gh, Cl,
      BfhT, BihT, BuhT, BohT, c3, h3, LOFF[3], LOFF[4], LOFF[5]);
  // L2 (65536, ratio 2)
  k_level<1><<<1024, 256, 0, stream>>>(sen, Ep, h3, c3,
      BfhT, BihT, BuhT, BohT, c2, h2, LOFF[2]);
  // L1 (16384, ratio 4)
  k_level<2><<<512, 256, 0, stream>>>(sen, Ep, h2, c2,
      BfhT, BihT, BuhT, BohT, c1, h1, LOFF[1]);
  // L0 (4096, ratio 4)
  k_level<2><<<128, 256, 0, stream>>>(sen, Ep, h1, c1,
      BfhT, BihT, BuhT, BohT, c0, h0, LOFF[0]);

  out_proj<<<64, 256, 0, stream>>>(h0, W_out, b_out, out);
}